// Round 7
// baseline (51.840 us; speedup 1.0000x reference)
//
#include <hip/hip_runtime.h>
#include <math.h>

#define BATCH 512
#define SEQL  2048
#define NPTS  (SEQL*3)        // 6144 points per batch
#define NFLT  (NPTS*3)        // 18432 floats per batch per tensor
#define NGRP  (NPTS/4)        // 1536 groups of 4 points
#define TPB   256             // 4 waves/block, 8 blocks/CU resident
#define NWAVE (TPB/64)
#define ITERS (NGRP/TPB)      // 6 groups per thread per pass

// ---------------- mask dtype handling ----------------
// flag: 0 = int32 {0,1}, 1 = uint8 {0,1}, 2 = float32
__device__ __forceinline__ int detect_flag(const void* cm, int* slds) {
    unsigned int v = ((const unsigned int*)cm)[threadIdx.x & 255];
    bool vi = (v <= 1u);
    bool vb = ((v & 0xFEFEFEFEu) == 0u);
    bool wi = __all(vi);
    bool wb = __all(vb);
    int wid = threadIdx.x >> 6;
    if ((threadIdx.x & 63) == 0) slds[wid] = (wi ? 1 : 0) | (wb ? 2 : 0);
    __syncthreads();
    if (threadIdx.x == 0) {
        int m = 3;
        for (int w = 0; w < (int)(blockDim.x >> 6); ++w) m &= slds[w];
        slds[8] = (m & 1) ? 0 : ((m & 2) ? 1 : 2);
    }
    __syncthreads();
    return slds[8];
}

__device__ __forceinline__ void load_mask4(const void* m, int flag, size_t g, float* w) {
    if (flag == 1) {
        unsigned int v = ((const unsigned int*)m)[g];
        w[0] = (v & 0x000000FFu) ? 1.f : 0.f;
        w[1] = (v & 0x0000FF00u) ? 1.f : 0.f;
        w[2] = (v & 0x00FF0000u) ? 1.f : 0.f;
        w[3] = (v & 0xFF000000u) ? 1.f : 0.f;
    } else if (flag == 0) {
        int4 v = ((const int4*)m)[g];
        w[0] = v.x ? 1.f : 0.f; w[1] = v.y ? 1.f : 0.f;
        w[2] = v.z ? 1.f : 0.f; w[3] = v.w ? 1.f : 0.f;
    } else {
        float4 v = ((const float4*)m)[g];
        w[0] = v.x != 0.f ? 1.f : 0.f; w[1] = v.y != 0.f ? 1.f : 0.f;
        w[2] = v.z != 0.f ? 1.f : 0.f; w[3] = v.w != 0.f ? 1.f : 0.f;
    }
}

// ---------------- reduction ----------------
template <int K>
__device__ __forceinline__ void block_reduce(float* acc, float* lds) {
#pragma unroll
    for (int k = 0; k < K; ++k) {
#pragma unroll
        for (int off = 32; off > 0; off >>= 1)
            acc[k] += __shfl_down(acc[k], off, 64);
    }
    int lane = threadIdx.x & 63;
    int wid  = threadIdx.x >> 6;
    if (lane == 0) {
#pragma unroll
        for (int k = 0; k < K; ++k) lds[wid * K + k] = acc[k];
    }
    __syncthreads();
    if (threadIdx.x == 0) {
#pragma unroll
        for (int k = 0; k < K; ++k) {
            float s = 0.f;
#pragma unroll
            for (int w = 0; w < NWAVE; ++w) s += lds[w * K + k];
            acc[k] = s;
        }
    }
}

__device__ __forceinline__ void accum_pt(float* a, float w,
                                         float px, float py, float pz,
                                         float qx, float qy, float qz) {
    a[0] += w;
    float wpx = w * px, wpy = w * py, wpz = w * pz;
    a[1] += wpx; a[2] += wpy; a[3] += wpz;
    a[4] += w * qx; a[5] += w * qy; a[6] += w * qz;
    a[7]  += wpx * qx; a[8]  += wpx * qy; a[9]  += wpx * qz;
    a[10] += wpy * qx; a[11] += wpy * qy; a[12] += wpy * qz;
    a[13] += wpz * qx; a[14] += wpz * qy; a[15] += wpz * qz;
}

// ---------------- closed-form 3x3 Kabsch (f64) ----------------
__device__ __forceinline__ void normalize3(double* v) {
    double n = sqrt(v[0] * v[0] + v[1] * v[1] + v[2] * v[2]);
    if (n > 1e-300) { v[0] /= n; v[1] /= n; v[2] /= n; }
}
__device__ __forceinline__ void cross3(const double* a, const double* b, double* c) {
    c[0] = a[1] * b[2] - a[2] * b[1];
    c[1] = a[2] * b[0] - a[0] * b[2];
    c[2] = a[0] * b[1] - a[1] * b[0];
}
// M = (A - aI)(A - bI)
__device__ __forceinline__ void proj_mul(const double A[3][3], double a, double b, double M[3][3]) {
    double X[3][3], Y[3][3];
#pragma unroll
    for (int i = 0; i < 3; ++i)
#pragma unroll
        for (int j = 0; j < 3; ++j) {
            X[i][j] = A[i][j] - (i == j ? a : 0.0);
            Y[i][j] = A[i][j] - (i == j ? b : 0.0);
        }
#pragma unroll
    for (int i = 0; i < 3; ++i)
#pragma unroll
        for (int j = 0; j < 3; ++j)
            M[i][j] = X[i][0] * Y[0][j] + X[i][1] * Y[1][j] + X[i][2] * Y[2][j];
}
__device__ __forceinline__ void best_col(const double M[3][3], double v[3]) {
    double n0 = M[0][0]*M[0][0] + M[1][0]*M[1][0] + M[2][0]*M[2][0];
    double n1 = M[0][1]*M[0][1] + M[1][1]*M[1][1] + M[2][1]*M[2][1];
    double n2 = M[0][2]*M[0][2] + M[1][2]*M[1][2] + M[2][2]*M[2][2];
    int j = (n0 >= n1 && n0 >= n2) ? 0 : (n1 >= n2 ? 1 : 2);
    v[0] = M[0][j]; v[1] = M[1][j]; v[2] = M[2][j];
}

__device__ void kabsch_params(const float* s, float* o) {
    double cnt = (double)s[0];
    double cs = fmax(cnt, 1.0);
    double mup[3], muq[3];
#pragma unroll
    for (int i = 0; i < 3; ++i) { mup[i] = (double)s[1 + i] / cs; muq[i] = (double)s[4 + i] / cs; }
    double Hm[3][3];
#pragma unroll
    for (int i = 0; i < 3; ++i)
#pragma unroll
        for (int j = 0; j < 3; ++j)
            Hm[i][j] = (double)s[7 + 3 * i + j] - cnt * mup[i] * muq[j];

    // A = H^T H (symmetric PSD)
    double A[3][3];
#pragma unroll
    for (int i = 0; i < 3; ++i)
#pragma unroll
        for (int j = 0; j < 3; ++j)
            A[i][j] = Hm[0][i] * Hm[0][j] + Hm[1][i] * Hm[1][j] + Hm[2][i] * Hm[2][j];

    // closed-form eigenvalues (descending), trig method
    double q3 = (A[0][0] + A[1][1] + A[2][2]) / 3.0;
    double pp1 = A[0][1]*A[0][1] + A[0][2]*A[0][2] + A[1][2]*A[1][2];
    double d0m = A[0][0]-q3, d1m = A[1][1]-q3, d2m = A[2][2]-q3;
    double pp2 = d0m*d0m + d1m*d1m + d2m*d2m + 2.0*pp1;
    double lam[3];
    double v1[3], v2[3], v3[3];
    if (pp2 <= 1e-24 * (q3*q3) + 1e-290) {
        lam[0] = lam[1] = lam[2] = q3;
        v1[0]=1; v1[1]=0; v1[2]=0;
        v2[0]=0; v2[1]=1; v2[2]=0;
        v3[0]=0; v3[1]=0; v3[2]=1;
    } else {
        double p = sqrt(pp2 / 6.0), invp = 1.0 / p;
        double B[3][3];
#pragma unroll
        for (int i = 0; i < 3; ++i)
#pragma unroll
            for (int j = 0; j < 3; ++j)
                B[i][j] = (A[i][j] - (i == j ? q3 : 0.0)) * invp;
        double detB = B[0][0]*(B[1][1]*B[2][2]-B[1][2]*B[2][1])
                    - B[0][1]*(B[1][0]*B[2][2]-B[1][2]*B[2][0])
                    + B[0][2]*(B[1][0]*B[2][1]-B[1][1]*B[2][0]);
        double r = detB * 0.5;
        r = fmin(1.0, fmax(-1.0, r));
        double phi = acos(r) / 3.0;
        lam[0] = q3 + 2.0 * p * cos(phi);
        lam[2] = q3 + 2.0 * p * cos(phi + 2.0943951023931953);  // +2pi/3
        lam[1] = 3.0 * q3 - lam[0] - lam[2];

        double M[3][3];
        proj_mul(A, lam[1], lam[2], M);
        best_col(M, v1);
        double n1v = sqrt(v1[0]*v1[0] + v1[1]*v1[1] + v1[2]*v1[2]);
        if (n1v > 1e-150) { v1[0]/=n1v; v1[1]/=n1v; v1[2]/=n1v; }
        else { v1[0]=1; v1[1]=0; v1[2]=0; }
        proj_mul(A, lam[0], lam[1], M);
        best_col(M, v3);
        double dot13 = v3[0]*v1[0] + v3[1]*v1[1] + v3[2]*v1[2];
        v3[0] -= dot13 * v1[0]; v3[1] -= dot13 * v1[1]; v3[2] -= dot13 * v1[2];
        double n3v = sqrt(v3[0]*v3[0] + v3[1]*v3[1] + v3[2]*v3[2]);
        if (n3v > 1e-150) { v3[0]/=n3v; v3[1]/=n3v; v3[2]/=n3v; }
        else {
            double a0 = fabs(v1[0]), a1 = fabs(v1[1]), a2 = fabs(v1[2]);
            double ax[3] = {0, 0, 0};
            if (a0 <= a1 && a0 <= a2) ax[0] = 1; else if (a1 <= a2) ax[1] = 1; else ax[2] = 1;
            double dd = ax[0]*v1[0] + ax[1]*v1[1] + ax[2]*v1[2];
            v3[0] = ax[0] - dd*v1[0]; v3[1] = ax[1] - dd*v1[1]; v3[2] = ax[2] - dd*v1[2];
            normalize3(v3);
        }
        cross3(v3, v1, v2);   // right-handed: v1 x v2 = v3
    }

    double Vs[3][3];
#pragma unroll
    for (int i = 0; i < 3; ++i) { Vs[i][0] = v1[i]; Vs[i][1] = v2[i]; Vs[i][2] = v3[i]; }
    double sv[3];
#pragma unroll
    for (int k = 0; k < 3; ++k) sv[k] = sqrt(fmax(lam[k], 0.0));

    double U[3][3];
    double eps = sv[0] * 1e-12 + 1e-300;
    for (int k = 0; k < 3; ++k) {
        double hv[3];
        for (int i = 0; i < 3; ++i)
            hv[i] = Hm[i][0] * Vs[0][k] + Hm[i][1] * Vs[1][k] + Hm[i][2] * Vs[2][k];
        if (sv[k] > eps) {
            double col[3] = {hv[0] / sv[k], hv[1] / sv[k], hv[2] / sv[k]};
            normalize3(col);
            for (int i = 0; i < 3; ++i) U[i][k] = col[i];
        } else if (k == 0) {
            U[0][0] = 1; U[1][0] = 0; U[2][0] = 0;
        } else if (k == 1) {
            double u0[3] = {U[0][0], U[1][0], U[2][0]};
            double ax[3] = {0, 0, 0};
            double a0 = fabs(u0[0]), a1 = fabs(u0[1]), a2 = fabs(u0[2]);
            if (a0 <= a1 && a0 <= a2) ax[0] = 1; else if (a1 <= a2) ax[1] = 1; else ax[2] = 1;
            double col[3]; cross3(u0, ax, col); normalize3(col);
            for (int i = 0; i < 3; ++i) U[i][1] = col[i];
        } else {
            double u0[3] = {U[0][0], U[1][0], U[2][0]};
            double u1[3] = {U[0][1], U[1][1], U[2][1]};
            double col[3]; cross3(u0, u1, col); normalize3(col);
            for (int i = 0; i < 3; ++i) U[i][2] = col[i];
        }
    }

    double detH = Hm[0][0] * (Hm[1][1] * Hm[2][2] - Hm[1][2] * Hm[2][1])
                - Hm[0][1] * (Hm[1][0] * Hm[2][2] - Hm[1][2] * Hm[2][0])
                + Hm[0][2] * (Hm[1][0] * Hm[2][1] - Hm[1][1] * Hm[2][0]);
    double e2 = (detH > 0.0) ? 1.0 : ((detH < 0.0) ? -1.0 : 0.0);

#pragma unroll
    for (int i = 0; i < 3; ++i)
#pragma unroll
        for (int j = 0; j < 3; ++j)
            o[3 * i + j] = (float)(Vs[i][0] * U[j][0] + Vs[i][1] * U[j][1] + e2 * Vs[i][2] * U[j][2]);

    double n = (double)s[16];
    double d0 = 1.24 * cbrt(fmax(n - 15.0, 1e-3)) - 1.8;
    d0 = fmax(d0, 1e-3);
#pragma unroll
    for (int i = 0; i < 3; ++i) { o[9 + i] = (float)mup[i]; o[12 + i] = (float)muq[i]; }
    o[15] = (float)(1.0 / (d0 * d0));
    o[16] = (float)cnt;
}

// ---------------- fused kernel: sums -> solve -> TM ----------------
// TPB=256 (4 waves) with min 8 blocks/CU: barriers stall only 1/8 of the
// CU's waves; one block's serial solve overlaps 7 other blocks' streaming.
__global__ __launch_bounds__(TPB, 8) void k_fused(
    const float* __restrict__ P, const float* __restrict__ Q,
    const void* __restrict__ cmask, const void* __restrict__ rmask,
    float* __restrict__ out) {
    int b = blockIdx.x;
    __shared__ int slds[9];
    __shared__ float lds[NWAVE * 17];
    __shared__ float prm[17];
    int flag = detect_flag(cmask, slds);

    const float4* Pv = (const float4*)(P + (size_t)b * NFLT);
    const float4* Qv = (const float4*)(Q + (size_t)b * NFLT);
    size_t gbase = (size_t)b * NGRP;

    // ---- phase A: masked sums ----
    float acc[17];
#pragma unroll
    for (int k = 0; k < 17; ++k) acc[k] = 0.0f;

    // residue count: SEQL/4 = 512 words, 2 per thread
#pragma unroll
    for (int it = 0; it < 2; ++it) {
        size_t rg = (size_t)b * (SEQL / 4) + threadIdx.x + it * TPB;
        if (flag == 1) {
            unsigned int v = ((const unsigned int*)rmask)[rg];
            acc[16] += (float)__popc(v);
        } else if (flag == 0) {
            int4 v = ((const int4*)rmask)[rg];
            acc[16] += (v.x ? 1.f : 0.f) + (v.y ? 1.f : 0.f) + (v.z ? 1.f : 0.f) + (v.w ? 1.f : 0.f);
        } else {
            float4 v = ((const float4*)rmask)[rg];
            acc[16] += (v.x != 0.f ? 1.f : 0.f) + (v.y != 0.f ? 1.f : 0.f)
                     + (v.z != 0.f ? 1.f : 0.f) + (v.w != 0.f ? 1.f : 0.f);
        }
    }

    for (int it = 0; it < ITERS; ++it) {
        int g = threadIdx.x + it * TPB;
        float4 p0 = Pv[3 * g + 0], p1 = Pv[3 * g + 1], p2 = Pv[3 * g + 2];
        float4 q0 = Qv[3 * g + 0], q1 = Qv[3 * g + 1], q2 = Qv[3 * g + 2];
        float w[4];
        load_mask4(cmask, flag, gbase + g, w);
        accum_pt(acc, w[0], p0.x, p0.y, p0.z, q0.x, q0.y, q0.z);
        accum_pt(acc, w[1], p0.w, p1.x, p1.y, q0.w, q1.x, q1.y);
        accum_pt(acc, w[2], p1.z, p1.w, p2.x, q1.z, q1.w, q2.x);
        accum_pt(acc, w[3], p2.y, p2.z, p2.w, q2.y, q2.z, q2.w);
    }

    block_reduce<17>(acc, lds);

    // ---- phase B: thread 0 runs closed-form Kabsch ----
    if (threadIdx.x == 0) kabsch_params(acc, prm);
    __syncthreads();

    float R0 = prm[0], R1 = prm[1], R2 = prm[2];
    float R3 = prm[3], R4 = prm[4], R5 = prm[5];
    float R6 = prm[6], R7 = prm[7], R8 = prm[8];
    float mpx = prm[9], mpy = prm[10], mpz = prm[11];
    float mqx = prm[12], mqy = prm[13], mqz = prm[14];
    float inv = prm[15], cnt = prm[16];

    // ---- phase C: rotate + TM (re-read, cache-resident) ----
    float acc2[1] = {0.0f};
    for (int it = 0; it < ITERS; ++it) {
        int g = threadIdx.x + it * TPB;
        float4 p0 = Pv[3 * g + 0], p1 = Pv[3 * g + 1], p2 = Pv[3 * g + 2];
        float4 q0 = Qv[3 * g + 0], q1 = Qv[3 * g + 1], q2 = Qv[3 * g + 2];
        float w[4];
        load_mask4(cmask, flag, gbase + g, w);
        float px[4] = {p0.x, p0.w, p1.z, p2.y};
        float py[4] = {p0.y, p1.x, p1.w, p2.z};
        float pz[4] = {p0.z, p1.y, p2.x, p2.w};
        float qx[4] = {q0.x, q0.w, q1.z, q2.y};
        float qy[4] = {q0.y, q1.x, q1.w, q2.z};
        float qz[4] = {q0.z, q1.y, q2.x, q2.w};
#pragma unroll
        for (int u = 0; u < 4; ++u) {
            float pcx = px[u] - mpx, pcy = py[u] - mpy, pcz = pz[u] - mpz;
            float ax = R0 * pcx + R1 * pcy + R2 * pcz;
            float ay = R3 * pcx + R4 * pcy + R5 * pcz;
            float az = R6 * pcx + R7 * pcy + R8 * pcz;
            float dx = ax - (qx[u] - mqx);
            float dy = ay - (qy[u] - mqy);
            float dz = az - (qz[u] - mqz);
            float d2 = dx * dx + dy * dy + dz * dz;
            acc2[0] += w[u] / (1.0f + d2 * inv);
        }
    }
    __syncthreads();   // lds reuse barrier
    block_reduce<1>(acc2, lds);
    if (threadIdx.x == 0)
        out[b] = (cnt > 0.0f) ? acc2[0] / fmaxf(cnt, 1.0f) : 0.0f;
}

// ---------------- launcher ----------------
extern "C" void kernel_launch(void* const* d_in, const int* in_sizes, int n_in,
                              void* d_out, int out_size, void* d_ws, size_t ws_size,
                              hipStream_t stream) {
    const float* P = (const float*)d_in[0];
    const float* Q = (const float*)d_in[1];
    const void* cm = d_in[2];
    const void* rm = d_in[3];
    float* out = (float*)d_out;

    k_fused<<<BATCH, TPB, 0, stream>>>(P, Q, cm, rm, out);
}

// Round 8
// 33.383 us; speedup vs baseline: 1.5529x; 1.5529x over previous
//
#include <hip/hip_runtime.h>
#include <math.h>

#define BATCH 512
#define SEQL  2048
#define NPTS  (SEQL*3)        // 6144 points per batch
#define NFLT  (NPTS*3)        // 18432 floats per batch per tensor
#define NGRP  (NPTS/4)        // 1536 groups of 4 points
#define TPB   512
#define NWAVE (TPB/64)
#define STASH 768             // groups kept in LDS for phase C (73.7 KB)

// ---------------- mask dtype handling ----------------
// flag: 0 = int32 {0,1}, 1 = uint8 {0,1}, 2 = float32
__device__ __forceinline__ int detect_flag(const void* cm, int* slds) {
    unsigned int v = ((const unsigned int*)cm)[threadIdx.x & 255];
    bool vi = (v <= 1u);
    bool vb = ((v & 0xFEFEFEFEu) == 0u);
    bool wi = __all(vi);
    bool wb = __all(vb);
    int wid = threadIdx.x >> 6;
    if ((threadIdx.x & 63) == 0) slds[wid] = (wi ? 1 : 0) | (wb ? 2 : 0);
    __syncthreads();
    if (threadIdx.x == 0) {
        int m = 3;
        for (int w = 0; w < (int)(blockDim.x >> 6); ++w) m &= slds[w];
        slds[8] = (m & 1) ? 0 : ((m & 2) ? 1 : 2);
    }
    __syncthreads();
    return slds[8];
}

__device__ __forceinline__ void load_mask4(const void* m, int flag, size_t g, float* w) {
    if (flag == 1) {
        unsigned int v = ((const unsigned int*)m)[g];
        w[0] = (v & 0x000000FFu) ? 1.f : 0.f;
        w[1] = (v & 0x0000FF00u) ? 1.f : 0.f;
        w[2] = (v & 0x00FF0000u) ? 1.f : 0.f;
        w[3] = (v & 0xFF000000u) ? 1.f : 0.f;
    } else if (flag == 0) {
        int4 v = ((const int4*)m)[g];
        w[0] = v.x ? 1.f : 0.f; w[1] = v.y ? 1.f : 0.f;
        w[2] = v.z ? 1.f : 0.f; w[3] = v.w ? 1.f : 0.f;
    } else {
        float4 v = ((const float4*)m)[g];
        w[0] = v.x != 0.f ? 1.f : 0.f; w[1] = v.y != 0.f ? 1.f : 0.f;
        w[2] = v.z != 0.f ? 1.f : 0.f; w[3] = v.w != 0.f ? 1.f : 0.f;
    }
}

// ---------------- reduction ----------------
template <int K>
__device__ __forceinline__ void block_reduce(float* acc, float* lds) {
#pragma unroll
    for (int k = 0; k < K; ++k) {
#pragma unroll
        for (int off = 32; off > 0; off >>= 1)
            acc[k] += __shfl_down(acc[k], off, 64);
    }
    int lane = threadIdx.x & 63;
    int wid  = threadIdx.x >> 6;
    if (lane == 0) {
#pragma unroll
        for (int k = 0; k < K; ++k) lds[wid * K + k] = acc[k];
    }
    __syncthreads();
    if (threadIdx.x == 0) {
#pragma unroll
        for (int k = 0; k < K; ++k) {
            float s = 0.f;
#pragma unroll
            for (int w = 0; w < NWAVE; ++w) s += lds[w * K + k];
            acc[k] = s;
        }
    }
}

__device__ __forceinline__ void accum_pt(float* a, float w,
                                         float px, float py, float pz,
                                         float qx, float qy, float qz) {
    a[0] += w;
    float wpx = w * px, wpy = w * py, wpz = w * pz;
    a[1] += wpx; a[2] += wpy; a[3] += wpz;
    a[4] += w * qx; a[5] += w * qy; a[6] += w * qz;
    a[7]  += wpx * qx; a[8]  += wpx * qy; a[9]  += wpx * qz;
    a[10] += wpy * qx; a[11] += wpy * qy; a[12] += wpy * qz;
    a[13] += wpz * qx; a[14] += wpz * qy; a[15] += wpz * qz;
}

// ---------------- closed-form 3x3 Kabsch, all scalars, no runtime indexing ----------------
__device__ void kabsch_params(const float* s, float* o) {
    double cnt = (double)s[0];
    double cs = fmax(cnt, 1.0);
    double mup0 = (double)s[1] / cs, mup1 = (double)s[2] / cs, mup2 = (double)s[3] / cs;
    double muq0 = (double)s[4] / cs, muq1 = (double)s[5] / cs, muq2 = (double)s[6] / cs;

    double h00 = (double)s[7]  - cnt * mup0 * muq0;
    double h01 = (double)s[8]  - cnt * mup0 * muq1;
    double h02 = (double)s[9]  - cnt * mup0 * muq2;
    double h10 = (double)s[10] - cnt * mup1 * muq0;
    double h11 = (double)s[11] - cnt * mup1 * muq1;
    double h12 = (double)s[12] - cnt * mup1 * muq2;
    double h20 = (double)s[13] - cnt * mup2 * muq0;
    double h21 = (double)s[14] - cnt * mup2 * muq1;
    double h22 = (double)s[15] - cnt * mup2 * muq2;

    // A = H^T H (symmetric): a_ij = sum_k h_ki h_kj
    double a00 = h00*h00 + h10*h10 + h20*h20;
    double a01 = h00*h01 + h10*h11 + h20*h21;
    double a02 = h00*h02 + h10*h12 + h20*h22;
    double a11 = h01*h01 + h11*h11 + h21*h21;
    double a12 = h01*h02 + h11*h12 + h21*h22;
    double a22 = h02*h02 + h12*h12 + h22*h22;

    double q3  = (a00 + a11 + a22) / 3.0;
    double pp1 = a01*a01 + a02*a02 + a12*a12;
    double b00 = a00 - q3, b11 = a11 - q3, b22 = a22 - q3;
    double pp2 = b00*b00 + b11*b11 + b22*b22 + 2.0 * pp1;

    double l0, l1, l2;
    double v1x, v1y, v1z, v2x, v2y, v2z, v3x, v3y, v3z;
    if (pp2 <= 1e-24 * (q3 * q3) + 1e-290) {
        l0 = l1 = l2 = q3;
        v1x = 1; v1y = 0; v1z = 0;
        v2x = 0; v2y = 1; v2z = 0;
        v3x = 0; v3y = 0; v3z = 1;
    } else {
        double p = sqrt(pp2 / 6.0), invp = 1.0 / p;
        double c00 = b00*invp, c01 = a01*invp, c02 = a02*invp;
        double c11 = b11*invp, c12 = a12*invp, c22 = b22*invp;
        double detB = c00*(c11*c22 - c12*c12) - c01*(c01*c22 - c12*c02)
                    + c02*(c01*c12 - c11*c02);
        double r = fmin(1.0, fmax(-1.0, detB * 0.5));
        double phi = acos(r) / 3.0;
        l0 = q3 + 2.0 * p * cos(phi);
        l2 = q3 + 2.0 * p * cos(phi + 2.0943951023931953);  // +2pi/3
        l1 = 3.0 * q3 - l0 - l2;

        // A*A (symmetric)
        double aa00 = a00*a00 + a01*a01 + a02*a02;
        double aa01 = a00*a01 + a01*a11 + a02*a12;
        double aa02 = a00*a02 + a01*a12 + a02*a22;
        double aa11 = a01*a01 + a11*a11 + a12*a12;
        double aa12 = a01*a02 + a11*a12 + a12*a22;
        double aa22 = a02*a02 + a12*a12 + a22*a22;

        // M1 = (A - l1 I)(A - l2 I) = A^2 - (l1+l2)A + l1 l2 I  -> eigvec of l0
        double s12 = l1 + l2, p12 = l1 * l2;
        double m00 = aa00 - s12*a00 + p12;
        double m01 = aa01 - s12*a01;
        double m02 = aa02 - s12*a02;
        double m11 = aa11 - s12*a11 + p12;
        double m12 = aa12 - s12*a12;
        double m22 = aa22 - s12*a22 + p12;
        double n0 = m00*m00 + m01*m01 + m02*m02;
        double n1 = m01*m01 + m11*m11 + m12*m12;
        double n2 = m02*m02 + m12*m12 + m22*m22;
        bool s0 = (n0 >= n1) && (n0 >= n2);
        bool sA = (n1 >= n2);
        v1x = s0 ? m00 : (sA ? m01 : m02);
        v1y = s0 ? m01 : (sA ? m11 : m12);
        v1z = s0 ? m02 : (sA ? m12 : m22);
        double n1v = sqrt(v1x*v1x + v1y*v1y + v1z*v1z);
        if (n1v > 1e-150) { v1x /= n1v; v1y /= n1v; v1z /= n1v; }
        else { v1x = 1; v1y = 0; v1z = 0; }

        // M3 = (A - l0 I)(A - l1 I) -> eigvec of l2
        double s01 = l0 + l1, p01 = l0 * l1;
        double t00 = aa00 - s01*a00 + p01;
        double t01 = aa01 - s01*a01;
        double t02 = aa02 - s01*a02;
        double t11 = aa11 - s01*a11 + p01;
        double t12 = aa12 - s01*a12;
        double t22 = aa22 - s01*a22 + p01;
        double u0n = t00*t00 + t01*t01 + t02*t02;
        double u1n = t01*t01 + t11*t11 + t12*t12;
        double u2n = t02*t02 + t12*t12 + t22*t22;
        bool d0c = (u0n >= u1n) && (u0n >= u2n);
        bool dA = (u1n >= u2n);
        v3x = d0c ? t00 : (dA ? t01 : t02);
        v3y = d0c ? t01 : (dA ? t11 : t12);
        v3z = d0c ? t02 : (dA ? t12 : t22);
        double dot13 = v3x*v1x + v3y*v1y + v3z*v1z;
        v3x -= dot13 * v1x; v3y -= dot13 * v1y; v3z -= dot13 * v1z;
        double n3v = sqrt(v3x*v3x + v3y*v3y + v3z*v3z);
        if (n3v > 1e-150) { v3x /= n3v; v3y /= n3v; v3z /= n3v; }
        else {
            double A0 = fabs(v1x), A1 = fabs(v1y), A2 = fabs(v1z);
            double axx = 0, axy = 0, axz = 0;
            if (A0 <= A1 && A0 <= A2) axx = 1; else if (A1 <= A2) axy = 1; else axz = 1;
            double dd = axx*v1x + axy*v1y + axz*v1z;
            v3x = axx - dd*v1x; v3y = axy - dd*v1y; v3z = axz - dd*v1z;
            double nn = sqrt(v3x*v3x + v3y*v3y + v3z*v3z);
            v3x /= nn; v3y /= nn; v3z /= nn;
        }
        // v2 = v3 x v1  (right-handed: v1 x v2 = v3)
        v2x = v3y*v1z - v3z*v1y;
        v2y = v3z*v1x - v3x*v1z;
        v2z = v3x*v1y - v3y*v1x;
    }

    double sv0 = sqrt(fmax(l0, 0.0));
    double sv1 = sqrt(fmax(l1, 0.0));
    double sv2 = sqrt(fmax(l2, 0.0));
    double eps = sv0 * 1e-12 + 1e-300;

    double u0x, u0y, u0z, u1x, u1y, u1z, u2x, u2y, u2z;
    // k = 0
    {
        double hx = h00*v1x + h01*v1y + h02*v1z;
        double hy = h10*v1x + h11*v1y + h12*v1z;
        double hz = h20*v1x + h21*v1y + h22*v1z;
        if (sv0 > eps) {
            double ix = hx / sv0, iy = hy / sv0, iz = hz / sv0;
            double nn = sqrt(ix*ix + iy*iy + iz*iz);
            if (nn > 1e-300) { ix /= nn; iy /= nn; iz /= nn; }
            u0x = ix; u0y = iy; u0z = iz;
        } else { u0x = 1; u0y = 0; u0z = 0; }
    }
    // k = 1
    {
        double hx = h00*v2x + h01*v2y + h02*v2z;
        double hy = h10*v2x + h11*v2y + h12*v2z;
        double hz = h20*v2x + h21*v2y + h22*v2z;
        if (sv1 > eps) {
            double ix = hx / sv1, iy = hy / sv1, iz = hz / sv1;
            double nn = sqrt(ix*ix + iy*iy + iz*iz);
            if (nn > 1e-300) { ix /= nn; iy /= nn; iz /= nn; }
            u1x = ix; u1y = iy; u1z = iz;
        } else {
            double A0 = fabs(u0x), A1 = fabs(u0y), A2 = fabs(u0z);
            double axx = 0, axy = 0, axz = 0;
            if (A0 <= A1 && A0 <= A2) axx = 1; else if (A1 <= A2) axy = 1; else axz = 1;
            // cross(u0, ax)
            double cx = u0y*axz - u0z*axy;
            double cy = u0z*axx - u0x*axz;
            double cz = u0x*axy - u0y*axx;
            double nn = sqrt(cx*cx + cy*cy + cz*cz);
            if (nn > 1e-300) { cx /= nn; cy /= nn; cz /= nn; }
            u1x = cx; u1y = cy; u1z = cz;
        }
    }
    // k = 2
    {
        double hx = h00*v3x + h01*v3y + h02*v3z;
        double hy = h10*v3x + h11*v3y + h12*v3z;
        double hz = h20*v3x + h21*v3y + h22*v3z;
        if (sv2 > eps) {
            double ix = hx / sv2, iy = hy / sv2, iz = hz / sv2;
            double nn = sqrt(ix*ix + iy*iy + iz*iz);
            if (nn > 1e-300) { ix /= nn; iy /= nn; iz /= nn; }
            u2x = ix; u2y = iy; u2z = iz;
        } else {
            u2x = u0y*u1z - u0z*u1y;
            u2y = u0z*u1x - u0x*u1z;
            u2z = u0x*u1y - u0y*u1x;
            double nn = sqrt(u2x*u2x + u2y*u2y + u2z*u2z);
            if (nn > 1e-300) { u2x /= nn; u2y /= nn; u2z /= nn; }
        }
    }

    double detH = h00*(h11*h22 - h12*h21) - h01*(h10*h22 - h12*h20)
                + h02*(h10*h21 - h11*h20);
    double e2 = (detH > 0.0) ? 1.0 : ((detH < 0.0) ? -1.0 : 0.0);

    // R[i][j] = v1_i*u0_j + v2_i*u1_j + e2*v3_i*u2_j
    o[0] = (float)(v1x*u0x + v2x*u1x + e2*v3x*u2x);
    o[1] = (float)(v1x*u0y + v2x*u1y + e2*v3x*u2y);
    o[2] = (float)(v1x*u0z + v2x*u1z + e2*v3x*u2z);
    o[3] = (float)(v1y*u0x + v2y*u1x + e2*v3y*u2x);
    o[4] = (float)(v1y*u0y + v2y*u1y + e2*v3y*u2y);
    o[5] = (float)(v1y*u0z + v2y*u1z + e2*v3y*u2z);
    o[6] = (float)(v1z*u0x + v2z*u1x + e2*v3z*u2x);
    o[7] = (float)(v1z*u0y + v2z*u1y + e2*v3z*u2y);
    o[8] = (float)(v1z*u0z + v2z*u1z + e2*v3z*u2z);

    double n = (double)s[16];
    double d0 = 1.24 * cbrt(fmax(n - 15.0, 1e-3)) - 1.8;
    d0 = fmax(d0, 1e-3);
    o[9]  = (float)mup0; o[10] = (float)mup1; o[11] = (float)mup2;
    o[12] = (float)muq0; o[13] = (float)muq1; o[14] = (float)muq2;
    o[15] = (float)(1.0 / (d0 * d0));
    o[16] = (float)cnt;
}

// ---------------- fused kernel: sums(+LDS stash) -> solve -> TM ----------------
__global__ __launch_bounds__(TPB, 4) void k_fused(
    const float* __restrict__ P, const float* __restrict__ Q,
    const void* __restrict__ cmask, const void* __restrict__ rmask,
    float* __restrict__ out) {
    int b = blockIdx.x;
    __shared__ int slds[9];
    __shared__ float lds[NWAVE * 17];
    __shared__ float prm[17];
    __shared__ float4 sP0[STASH], sP1[STASH], sP2[STASH];
    __shared__ float4 sQ0[STASH], sQ1[STASH], sQ2[STASH];
    int flag = detect_flag(cmask, slds);

    const float4* Pv = (const float4*)(P + (size_t)b * NFLT);
    const float4* Qv = (const float4*)(Q + (size_t)b * NFLT);
    size_t gbase = (size_t)b * NGRP;

    // ---- phase A: masked sums + stash first STASH groups in LDS ----
    float acc[17];
#pragma unroll
    for (int k = 0; k < 17; ++k) acc[k] = 0.0f;

    {   // residue count: SEQL/4 = 512 words, one per thread
        size_t rg = (size_t)b * (SEQL / 4) + threadIdx.x;
        if (flag == 1) {
            unsigned int v = ((const unsigned int*)rmask)[rg];
            acc[16] = (float)__popc(v);
        } else if (flag == 0) {
            int4 v = ((const int4*)rmask)[rg];
            acc[16] = (v.x ? 1.f : 0.f) + (v.y ? 1.f : 0.f) + (v.z ? 1.f : 0.f) + (v.w ? 1.f : 0.f);
        } else {
            float4 v = ((const float4*)rmask)[rg];
            acc[16] = (v.x != 0.f ? 1.f : 0.f) + (v.y != 0.f ? 1.f : 0.f)
                    + (v.z != 0.f ? 1.f : 0.f) + (v.w != 0.f ? 1.f : 0.f);
        }
    }

#pragma unroll
    for (int it = 0; it < 3; ++it) {
        int g = threadIdx.x + it * TPB;
        float4 p0 = Pv[3 * g + 0], p1 = Pv[3 * g + 1], p2 = Pv[3 * g + 2];
        float4 q0 = Qv[3 * g + 0], q1 = Qv[3 * g + 1], q2 = Qv[3 * g + 2];
        float w[4];
        load_mask4(cmask, flag, gbase + g, w);
        if (g < STASH) {    // wave-uniform (wave boundaries align with 768)
            sP0[g] = p0; sP1[g] = p1; sP2[g] = p2;
            sQ0[g] = q0; sQ1[g] = q1; sQ2[g] = q2;
        }
        accum_pt(acc, w[0], p0.x, p0.y, p0.z, q0.x, q0.y, q0.z);
        accum_pt(acc, w[1], p0.w, p1.x, p1.y, q0.w, q1.x, q1.y);
        accum_pt(acc, w[2], p1.z, p1.w, p2.x, q1.z, q1.w, q2.x);
        accum_pt(acc, w[3], p2.y, p2.z, p2.w, q2.y, q2.z, q2.w);
    }

    block_reduce<17>(acc, lds);

    // ---- phase B: thread 0, scratch-free closed-form Kabsch ----
    if (threadIdx.x == 0) kabsch_params(acc, prm);
    __syncthreads();

    float R0 = prm[0], R1 = prm[1], R2 = prm[2];
    float R3 = prm[3], R4 = prm[4], R5 = prm[5];
    float R6 = prm[6], R7 = prm[7], R8 = prm[8];
    float mpx = prm[9], mpy = prm[10], mpz = prm[11];
    float mqx = prm[12], mqy = prm[13], mqz = prm[14];
    float inv = prm[15], cnt = prm[16];

    // ---- phase C: rotate + TM; 50% from LDS, 50% from L3 ----
    float acc2[1] = {0.0f};
#pragma unroll
    for (int it = 0; it < 3; ++it) {
        int g = threadIdx.x + it * TPB;
        float4 p0, p1, p2, q0, q1, q2;
        if (g < STASH) {    // wave-uniform
            p0 = sP0[g]; p1 = sP1[g]; p2 = sP2[g];
            q0 = sQ0[g]; q1 = sQ1[g]; q2 = sQ2[g];
        } else {
            p0 = Pv[3 * g + 0]; p1 = Pv[3 * g + 1]; p2 = Pv[3 * g + 2];
            q0 = Qv[3 * g + 0]; q1 = Qv[3 * g + 1]; q2 = Qv[3 * g + 2];
        }
        float w[4];
        load_mask4(cmask, flag, gbase + g, w);
        float px[4] = {p0.x, p0.w, p1.z, p2.y};
        float py[4] = {p0.y, p1.x, p1.w, p2.z};
        float pz[4] = {p0.z, p1.y, p2.x, p2.w};
        float qx[4] = {q0.x, q0.w, q1.z, q2.y};
        float qy[4] = {q0.y, q1.x, q1.w, q2.z};
        float qz[4] = {q0.z, q1.y, q2.x, q2.w};
#pragma unroll
        for (int u = 0; u < 4; ++u) {
            float pcx = px[u] - mpx, pcy = py[u] - mpy, pcz = pz[u] - mpz;
            float ax = R0 * pcx + R1 * pcy + R2 * pcz;
            float ay = R3 * pcx + R4 * pcy + R5 * pcz;
            float az = R6 * pcx + R7 * pcy + R8 * pcz;
            float dx = ax - (qx[u] - mqx);
            float dy = ay - (qy[u] - mqy);
            float dz = az - (qz[u] - mqz);
            float d2 = dx * dx + dy * dy + dz * dz;
            acc2[0] += w[u] / (1.0f + d2 * inv);
        }
    }
    __syncthreads();   // lds reuse barrier
    block_reduce<1>(acc2, lds);
    if (threadIdx.x == 0)
        out[b] = (cnt > 0.0f) ? acc2[0] / fmaxf(cnt, 1.0f) : 0.0f;
}

// ---------------- launcher ----------------
extern "C" void kernel_launch(void* const* d_in, const int* in_sizes, int n_in,
                              void* d_out, int out_size, void* d_ws, size_t ws_size,
                              hipStream_t stream) {
    const float* P = (const float*)d_in[0];
    const float* Q = (const float*)d_in[1];
    const void* cm = d_in[2];
    const void* rm = d_in[3];
    float* out = (float*)d_out;

    k_fused<<<BATCH, TPB, 0, stream>>>(P, Q, cm, rm, out);
}

// Round 9
// 30.115 us; speedup vs baseline: 1.7214x; 1.1085x over previous
//
#include <hip/hip_runtime.h>
#include <math.h>

#define BATCH 512
#define SEQL  2048
#define NPTS  (SEQL*3)        // 6144 points per batch
#define NFLT  (NPTS*3)        // 18432 floats per batch per tensor
#define NGRP  (NPTS/4)        // 1536 groups of 4 points
#define TPB   512
#define NWAVE (TPB/64)
#define STASH 768             // groups kept in LDS for phase C (73.7 KB)

// ---------------- mask dtype detection ----------------
// flag: 0 = int32 {0,1}, 1 = uint8 {0,1}, 2 = float32
__device__ __forceinline__ int detect_flag(const void* cm, int* slds) {
    unsigned int v = ((const unsigned int*)cm)[threadIdx.x & 255];
    bool vi = (v <= 1u);
    bool vb = ((v & 0xFEFEFEFEu) == 0u);
    bool wi = __all(vi);
    bool wb = __all(vb);
    int wid = threadIdx.x >> 6;
    if ((threadIdx.x & 63) == 0) slds[wid] = (wi ? 1 : 0) | (wb ? 2 : 0);
    __syncthreads();
    if (threadIdx.x == 0) {
        int m = 3;
        for (int w = 0; w < (int)(blockDim.x >> 6); ++w) m &= slds[w];
        slds[8] = (m & 1) ? 0 : ((m & 2) ? 1 : 2);
    }
    __syncthreads();
    return slds[8];
}

__device__ __forceinline__ void load_mask4(const void* m, int flag, size_t g, float* w) {
    if (flag == 1) {
        unsigned int v = ((const unsigned int*)m)[g];
        w[0] = (v & 0x000000FFu) ? 1.f : 0.f;
        w[1] = (v & 0x0000FF00u) ? 1.f : 0.f;
        w[2] = (v & 0x00FF0000u) ? 1.f : 0.f;
        w[3] = (v & 0xFF000000u) ? 1.f : 0.f;
    } else if (flag == 0) {
        int4 v = ((const int4*)m)[g];
        w[0] = v.x ? 1.f : 0.f; w[1] = v.y ? 1.f : 0.f;
        w[2] = v.z ? 1.f : 0.f; w[3] = v.w ? 1.f : 0.f;
    } else {
        float4 v = ((const float4*)m)[g];
        w[0] = v.x != 0.f ? 1.f : 0.f; w[1] = v.y != 0.f ? 1.f : 0.f;
        w[2] = v.z != 0.f ? 1.f : 0.f; w[3] = v.w != 0.f ? 1.f : 0.f;
    }
}

// ---------------- reduction ----------------
template <int K>
__device__ __forceinline__ void block_reduce(float* acc, float* lds) {
#pragma unroll
    for (int k = 0; k < K; ++k) {
#pragma unroll
        for (int off = 32; off > 0; off >>= 1)
            acc[k] += __shfl_down(acc[k], off, 64);
    }
    int lane = threadIdx.x & 63;
    int wid  = threadIdx.x >> 6;
    if (lane == 0) {
#pragma unroll
        for (int k = 0; k < K; ++k) lds[wid * K + k] = acc[k];
    }
    __syncthreads();
    if (threadIdx.x == 0) {
#pragma unroll
        for (int k = 0; k < K; ++k) {
            float s = 0.f;
#pragma unroll
            for (int w = 0; w < NWAVE; ++w) s += lds[w * K + k];
            acc[k] = s;
        }
    }
}

__device__ __forceinline__ void accum_pt(float* a, float w,
                                         float px, float py, float pz,
                                         float qx, float qy, float qz) {
    a[0] += w;
    float wpx = w * px, wpy = w * py, wpz = w * pz;
    a[1] += wpx; a[2] += wpy; a[3] += wpz;
    a[4] += w * qx; a[5] += w * qy; a[6] += w * qz;
    a[7]  += wpx * qx; a[8]  += wpx * qy; a[9]  += wpx * qz;
    a[10] += wpy * qx; a[11] += wpy * qy; a[12] += wpy * qz;
    a[13] += wpz * qx; a[14] += wpz * qy; a[15] += wpz * qz;
}

// ---------------- closed-form 3x3 Kabsch, all scalars, no runtime indexing ----
// out prm: [0..8]=R, [9..11]=t (R*muP - muQ), [12]=1/d0^2, [13]=cnt
__device__ void kabsch_params(const float* s, float* o) {
    double cnt = (double)s[0];
    double cs = fmax(cnt, 1.0);
    double mup0 = (double)s[1] / cs, mup1 = (double)s[2] / cs, mup2 = (double)s[3] / cs;
    double muq0 = (double)s[4] / cs, muq1 = (double)s[5] / cs, muq2 = (double)s[6] / cs;

    double h00 = (double)s[7]  - cnt * mup0 * muq0;
    double h01 = (double)s[8]  - cnt * mup0 * muq1;
    double h02 = (double)s[9]  - cnt * mup0 * muq2;
    double h10 = (double)s[10] - cnt * mup1 * muq0;
    double h11 = (double)s[11] - cnt * mup1 * muq1;
    double h12 = (double)s[12] - cnt * mup1 * muq2;
    double h20 = (double)s[13] - cnt * mup2 * muq0;
    double h21 = (double)s[14] - cnt * mup2 * muq1;
    double h22 = (double)s[15] - cnt * mup2 * muq2;

    double a00 = h00*h00 + h10*h10 + h20*h20;
    double a01 = h00*h01 + h10*h11 + h20*h21;
    double a02 = h00*h02 + h10*h12 + h20*h22;
    double a11 = h01*h01 + h11*h11 + h21*h21;
    double a12 = h01*h02 + h11*h12 + h21*h22;
    double a22 = h02*h02 + h12*h12 + h22*h22;

    double q3  = (a00 + a11 + a22) / 3.0;
    double pp1 = a01*a01 + a02*a02 + a12*a12;
    double b00 = a00 - q3, b11 = a11 - q3, b22 = a22 - q3;
    double pp2 = b00*b00 + b11*b11 + b22*b22 + 2.0 * pp1;

    double l0, l1, l2;
    double v1x, v1y, v1z, v2x, v2y, v2z, v3x, v3y, v3z;
    if (pp2 <= 1e-24 * (q3 * q3) + 1e-290) {
        l0 = l1 = l2 = q3;
        v1x = 1; v1y = 0; v1z = 0;
        v2x = 0; v2y = 1; v2z = 0;
        v3x = 0; v3y = 0; v3z = 1;
    } else {
        double p = sqrt(pp2 / 6.0), invp = 1.0 / p;
        double c00 = b00*invp, c01 = a01*invp, c02 = a02*invp;
        double c11 = b11*invp, c12 = a12*invp, c22 = b22*invp;
        double detB = c00*(c11*c22 - c12*c12) - c01*(c01*c22 - c12*c02)
                    + c02*(c01*c12 - c11*c02);
        double r = fmin(1.0, fmax(-1.0, detB * 0.5));
        double phi = acos(r) / 3.0;
        l0 = q3 + 2.0 * p * cos(phi);
        l2 = q3 + 2.0 * p * cos(phi + 2.0943951023931953);  // +2pi/3
        l1 = 3.0 * q3 - l0 - l2;

        double aa00 = a00*a00 + a01*a01 + a02*a02;
        double aa01 = a00*a01 + a01*a11 + a02*a12;
        double aa02 = a00*a02 + a01*a12 + a02*a22;
        double aa11 = a01*a01 + a11*a11 + a12*a12;
        double aa12 = a01*a02 + a11*a12 + a12*a22;
        double aa22 = a02*a02 + a12*a12 + a22*a22;

        double s12 = l1 + l2, p12 = l1 * l2;
        double m00 = aa00 - s12*a00 + p12;
        double m01 = aa01 - s12*a01;
        double m02 = aa02 - s12*a02;
        double m11 = aa11 - s12*a11 + p12;
        double m12 = aa12 - s12*a12;
        double m22 = aa22 - s12*a22 + p12;
        double n0 = m00*m00 + m01*m01 + m02*m02;
        double n1 = m01*m01 + m11*m11 + m12*m12;
        double n2 = m02*m02 + m12*m12 + m22*m22;
        bool s0 = (n0 >= n1) && (n0 >= n2);
        bool sA = (n1 >= n2);
        v1x = s0 ? m00 : (sA ? m01 : m02);
        v1y = s0 ? m01 : (sA ? m11 : m12);
        v1z = s0 ? m02 : (sA ? m12 : m22);
        double n1v = sqrt(v1x*v1x + v1y*v1y + v1z*v1z);
        if (n1v > 1e-150) { v1x /= n1v; v1y /= n1v; v1z /= n1v; }
        else { v1x = 1; v1y = 0; v1z = 0; }

        double s01 = l0 + l1, p01 = l0 * l1;
        double t00 = aa00 - s01*a00 + p01;
        double t01 = aa01 - s01*a01;
        double t02 = aa02 - s01*a02;
        double t11 = aa11 - s01*a11 + p01;
        double t12 = aa12 - s01*a12;
        double t22 = aa22 - s01*a22 + p01;
        double u0n = t00*t00 + t01*t01 + t02*t02;
        double u1n = t01*t01 + t11*t11 + t12*t12;
        double u2n = t02*t02 + t12*t12 + t22*t22;
        bool d0c = (u0n >= u1n) && (u0n >= u2n);
        bool dA = (u1n >= u2n);
        v3x = d0c ? t00 : (dA ? t01 : t02);
        v3y = d0c ? t01 : (dA ? t11 : t12);
        v3z = d0c ? t02 : (dA ? t12 : t22);
        double dot13 = v3x*v1x + v3y*v1y + v3z*v1z;
        v3x -= dot13 * v1x; v3y -= dot13 * v1y; v3z -= dot13 * v1z;
        double n3v = sqrt(v3x*v3x + v3y*v3y + v3z*v3z);
        if (n3v > 1e-150) { v3x /= n3v; v3y /= n3v; v3z /= n3v; }
        else {
            double A0 = fabs(v1x), A1 = fabs(v1y), A2 = fabs(v1z);
            double axx = 0, axy = 0, axz = 0;
            if (A0 <= A1 && A0 <= A2) axx = 1; else if (A1 <= A2) axy = 1; else axz = 1;
            double dd = axx*v1x + axy*v1y + axz*v1z;
            v3x = axx - dd*v1x; v3y = axy - dd*v1y; v3z = axz - dd*v1z;
            double nn = sqrt(v3x*v3x + v3y*v3y + v3z*v3z);
            v3x /= nn; v3y /= nn; v3z /= nn;
        }
        v2x = v3y*v1z - v3z*v1y;
        v2y = v3z*v1x - v3x*v1z;
        v2z = v3x*v1y - v3y*v1x;
    }

    double sv0 = sqrt(fmax(l0, 0.0));
    double sv1 = sqrt(fmax(l1, 0.0));
    double sv2 = sqrt(fmax(l2, 0.0));
    double eps = sv0 * 1e-12 + 1e-300;

    double u0x, u0y, u0z, u1x, u1y, u1z, u2x, u2y, u2z;
    {
        double hx = h00*v1x + h01*v1y + h02*v1z;
        double hy = h10*v1x + h11*v1y + h12*v1z;
        double hz = h20*v1x + h21*v1y + h22*v1z;
        if (sv0 > eps) {
            double ix = hx / sv0, iy = hy / sv0, iz = hz / sv0;
            double nn = sqrt(ix*ix + iy*iy + iz*iz);
            if (nn > 1e-300) { ix /= nn; iy /= nn; iz /= nn; }
            u0x = ix; u0y = iy; u0z = iz;
        } else { u0x = 1; u0y = 0; u0z = 0; }
    }
    {
        double hx = h00*v2x + h01*v2y + h02*v2z;
        double hy = h10*v2x + h11*v2y + h12*v2z;
        double hz = h20*v2x + h21*v2y + h22*v2z;
        if (sv1 > eps) {
            double ix = hx / sv1, iy = hy / sv1, iz = hz / sv1;
            double nn = sqrt(ix*ix + iy*iy + iz*iz);
            if (nn > 1e-300) { ix /= nn; iy /= nn; iz /= nn; }
            u1x = ix; u1y = iy; u1z = iz;
        } else {
            double A0 = fabs(u0x), A1 = fabs(u0y), A2 = fabs(u0z);
            double axx = 0, axy = 0, axz = 0;
            if (A0 <= A1 && A0 <= A2) axx = 1; else if (A1 <= A2) axy = 1; else axz = 1;
            double cx = u0y*axz - u0z*axy;
            double cy = u0z*axx - u0x*axz;
            double cz = u0x*axy - u0y*axx;
            double nn = sqrt(cx*cx + cy*cy + cz*cz);
            if (nn > 1e-300) { cx /= nn; cy /= nn; cz /= nn; }
            u1x = cx; u1y = cy; u1z = cz;
        }
    }
    {
        double hx = h00*v3x + h01*v3y + h02*v3z;
        double hy = h10*v3x + h11*v3y + h12*v3z;
        double hz = h20*v3x + h21*v3y + h22*v3z;
        if (sv2 > eps) {
            double ix = hx / sv2, iy = hy / sv2, iz = hz / sv2;
            double nn = sqrt(ix*ix + iy*iy + iz*iz);
            if (nn > 1e-300) { ix /= nn; iy /= nn; iz /= nn; }
            u2x = ix; u2y = iy; u2z = iz;
        } else {
            u2x = u0y*u1z - u0z*u1y;
            u2y = u0z*u1x - u0x*u1z;
            u2z = u0x*u1y - u0y*u1x;
            double nn = sqrt(u2x*u2x + u2y*u2y + u2z*u2z);
            if (nn > 1e-300) { u2x /= nn; u2y /= nn; u2z /= nn; }
        }
    }

    double detH = h00*(h11*h22 - h12*h21) - h01*(h10*h22 - h12*h20)
                + h02*(h10*h21 - h11*h20);
    double e2 = (detH > 0.0) ? 1.0 : ((detH < 0.0) ? -1.0 : 0.0);

    double R00 = v1x*u0x + v2x*u1x + e2*v3x*u2x;
    double R01 = v1x*u0y + v2x*u1y + e2*v3x*u2y;
    double R02 = v1x*u0z + v2x*u1z + e2*v3x*u2z;
    double R10 = v1y*u0x + v2y*u1x + e2*v3y*u2x;
    double R11 = v1y*u0y + v2y*u1y + e2*v3y*u2y;
    double R12 = v1y*u0z + v2y*u1z + e2*v3y*u2z;
    double R20 = v1z*u0x + v2z*u1x + e2*v3z*u2x;
    double R21 = v1z*u0y + v2z*u1y + e2*v3z*u2y;
    double R22 = v1z*u0z + v2z*u1z + e2*v3z*u2z;

    o[0] = (float)R00; o[1] = (float)R01; o[2] = (float)R02;
    o[3] = (float)R10; o[4] = (float)R11; o[5] = (float)R12;
    o[6] = (float)R20; o[7] = (float)R21; o[8] = (float)R22;

    // t = R*muP - muQ  (phase C uses d = R*p - t - q)
    o[9]  = (float)(R00*mup0 + R01*mup1 + R02*mup2 - muq0);
    o[10] = (float)(R10*mup0 + R11*mup1 + R12*mup2 - muq1);
    o[11] = (float)(R20*mup0 + R21*mup1 + R22*mup2 - muq2);

    double n = (double)s[16];
    double d0 = 1.24 * cbrt(fmax(n - 15.0, 1e-3)) - 1.8;
    d0 = fmax(d0, 1e-3);
    o[12] = (float)(1.0 / (d0 * d0));
    o[13] = (float)cnt;
}

// ---------------- fused kernel ----------------
__global__ __launch_bounds__(TPB, 4) void k_fused(
    const float* __restrict__ P, const float* __restrict__ Q,
    const void* __restrict__ cmask, const void* __restrict__ rmask,
    float* __restrict__ out) {
    int b = blockIdx.x;
    int tid = threadIdx.x;
    __shared__ int slds[9];
    __shared__ float lds[NWAVE * 17];
    __shared__ float prm[14];
    __shared__ float4 sP0[STASH], sP1[STASH], sP2[STASH];
    __shared__ float4 sQ0[STASH], sQ1[STASH], sQ2[STASH];
    int flag = detect_flag(cmask, slds);

    const float4* Pv = (const float4*)(P + (size_t)b * NFLT);
    const float4* Qv = (const float4*)(Q + (size_t)b * NFLT);
    size_t gbase = (size_t)b * NGRP;

    // ---- phase A: hoist ALL loads, then accumulate ----
    float4 p[9], q[9];
#pragma unroll
    for (int k = 0; k < 3; ++k) {
        int g = tid + k * TPB;
        p[3*k+0] = Pv[3*g+0]; p[3*k+1] = Pv[3*g+1]; p[3*k+2] = Pv[3*g+2];
        q[3*k+0] = Qv[3*g+0]; q[3*k+1] = Qv[3*g+1]; q[3*k+2] = Qv[3*g+2];
    }
    float w[12];
    float rescnt;
    {
        size_t rg = (size_t)b * (SEQL / 4) + tid;
        if (flag == 0) {
            const int4* cm4 = (const int4*)cmask;
            int4 m0 = cm4[gbase + tid], m1 = cm4[gbase + tid + TPB], m2 = cm4[gbase + tid + 2*TPB];
            int4 rv = ((const int4*)rmask)[rg];
            w[0]=m0.x?1.f:0.f; w[1]=m0.y?1.f:0.f; w[2]=m0.z?1.f:0.f; w[3]=m0.w?1.f:0.f;
            w[4]=m1.x?1.f:0.f; w[5]=m1.y?1.f:0.f; w[6]=m1.z?1.f:0.f; w[7]=m1.w?1.f:0.f;
            w[8]=m2.x?1.f:0.f; w[9]=m2.y?1.f:0.f; w[10]=m2.z?1.f:0.f; w[11]=m2.w?1.f:0.f;
            rescnt = (rv.x?1.f:0.f) + (rv.y?1.f:0.f) + (rv.z?1.f:0.f) + (rv.w?1.f:0.f);
        } else if (flag == 1) {
            const unsigned int* cmw = (const unsigned int*)cmask;
            unsigned int m0 = cmw[gbase + tid], m1 = cmw[gbase + tid + TPB], m2 = cmw[gbase + tid + 2*TPB];
            unsigned int rv = ((const unsigned int*)rmask)[rg];
            w[0]=(m0&0xFFu)?1.f:0.f; w[1]=(m0&0xFF00u)?1.f:0.f; w[2]=(m0&0xFF0000u)?1.f:0.f; w[3]=(m0&0xFF000000u)?1.f:0.f;
            w[4]=(m1&0xFFu)?1.f:0.f; w[5]=(m1&0xFF00u)?1.f:0.f; w[6]=(m1&0xFF0000u)?1.f:0.f; w[7]=(m1&0xFF000000u)?1.f:0.f;
            w[8]=(m2&0xFFu)?1.f:0.f; w[9]=(m2&0xFF00u)?1.f:0.f; w[10]=(m2&0xFF0000u)?1.f:0.f; w[11]=(m2&0xFF000000u)?1.f:0.f;
            rescnt = (float)__popc(rv);
        } else {
            const float4* cmf = (const float4*)cmask;
            float4 m0 = cmf[gbase + tid], m1 = cmf[gbase + tid + TPB], m2 = cmf[gbase + tid + 2*TPB];
            float4 rv = ((const float4*)rmask)[rg];
            w[0]=m0.x!=0.f?1.f:0.f; w[1]=m0.y!=0.f?1.f:0.f; w[2]=m0.z!=0.f?1.f:0.f; w[3]=m0.w!=0.f?1.f:0.f;
            w[4]=m1.x!=0.f?1.f:0.f; w[5]=m1.y!=0.f?1.f:0.f; w[6]=m1.z!=0.f?1.f:0.f; w[7]=m1.w!=0.f?1.f:0.f;
            w[8]=m2.x!=0.f?1.f:0.f; w[9]=m2.y!=0.f?1.f:0.f; w[10]=m2.z!=0.f?1.f:0.f; w[11]=m2.w!=0.f?1.f:0.f;
            rescnt = (rv.x!=0.f?1.f:0.f) + (rv.y!=0.f?1.f:0.f) + (rv.z!=0.f?1.f:0.f) + (rv.w!=0.f?1.f:0.f);
        }
    }

    // stash first STASH groups (each thread writes only its own entries)
#pragma unroll
    for (int k = 0; k < 3; ++k) {
        int g = tid + k * TPB;
        if (g < STASH) {    // wave-uniform
            sP0[g] = p[3*k+0]; sP1[g] = p[3*k+1]; sP2[g] = p[3*k+2];
            sQ0[g] = q[3*k+0]; sQ1[g] = q[3*k+1]; sQ2[g] = q[3*k+2];
        }
    }

    float acc[17];
#pragma unroll
    for (int k = 0; k < 17; ++k) acc[k] = 0.0f;
    acc[16] = rescnt;

#pragma unroll
    for (int k = 0; k < 3; ++k) {
        float4 p0 = p[3*k+0], p1 = p[3*k+1], p2 = p[3*k+2];
        float4 q0 = q[3*k+0], q1 = q[3*k+1], q2 = q[3*k+2];
        accum_pt(acc, w[4*k+0], p0.x, p0.y, p0.z, q0.x, q0.y, q0.z);
        accum_pt(acc, w[4*k+1], p0.w, p1.x, p1.y, q0.w, q1.x, q1.y);
        accum_pt(acc, w[4*k+2], p1.z, p1.w, p2.x, q1.z, q1.w, q2.x);
        accum_pt(acc, w[4*k+3], p2.y, p2.z, p2.w, q2.y, q2.z, q2.w);
    }

    block_reduce<17>(acc, lds);

    // ---- phase B: thread 0, scratch-free closed-form Kabsch ----
    if (tid == 0) kabsch_params(acc, prm);
    __syncthreads();

    float R0 = prm[0], R1 = prm[1], R2 = prm[2];
    float R3 = prm[3], R4 = prm[4], R5 = prm[5];
    float R6 = prm[6], R7 = prm[7], R8 = prm[8];
    float tx = prm[9], ty = prm[10], tz = prm[11];
    float inv = prm[12], cnt = prm[13];

    // ---- phase C: issue global (non-stash) loads first, then LDS half ----
    // groups: g0=tid (LDS), g1=tid+512 (LDS if tid<256, else global), g2=tid+1024 (global)
    bool lds1 = (tid < STASH - TPB);   // wave-uniform
    float4 gp0, gp1, gp2, gq0, gq1, gq2;   // g2
    float4 hp0, hp1, hp2, hq0, hq1, hq2;   // g1 when global
    {
        int g = tid + 2 * TPB;
        gp0 = Pv[3*g+0]; gp1 = Pv[3*g+1]; gp2 = Pv[3*g+2];
        gq0 = Qv[3*g+0]; gq1 = Qv[3*g+1]; gq2 = Qv[3*g+2];
    }
    if (!lds1) {
        int g = tid + TPB;
        hp0 = Pv[3*g+0]; hp1 = Pv[3*g+1]; hp2 = Pv[3*g+2];
        hq0 = Qv[3*g+0]; hq1 = Qv[3*g+1]; hq2 = Qv[3*g+2];
    }

    float acc2 = 0.0f;
#pragma unroll
    for (int k = 0; k < 3; ++k) {
        int g = tid + k * TPB;
        float4 p0, p1, p2, q0, q1, q2;
        if (k == 0) {
            p0 = sP0[g]; p1 = sP1[g]; p2 = sP2[g];
            q0 = sQ0[g]; q1 = sQ1[g]; q2 = sQ2[g];
        } else if (k == 1) {
            if (lds1) {
                p0 = sP0[g]; p1 = sP1[g]; p2 = sP2[g];
                q0 = sQ0[g]; q1 = sQ1[g]; q2 = sQ2[g];
            } else {
                p0 = hp0; p1 = hp1; p2 = hp2;
                q0 = hq0; q1 = hq1; q2 = hq2;
            }
        } else {
            p0 = gp0; p1 = gp1; p2 = gp2;
            q0 = gq0; q1 = gq1; q2 = gq2;
        }
        float px[4] = {p0.x, p0.w, p1.z, p2.y};
        float py[4] = {p0.y, p1.x, p1.w, p2.z};
        float pz[4] = {p0.z, p1.y, p2.x, p2.w};
        float qx[4] = {q0.x, q0.w, q1.z, q2.y};
        float qy[4] = {q0.y, q1.x, q1.w, q2.z};
        float qz[4] = {q0.z, q1.y, q2.x, q2.w};
#pragma unroll
        for (int u = 0; u < 4; ++u) {
            float dx = R0*px[u] + R1*py[u] + R2*pz[u] - tx - qx[u];
            float dy = R3*px[u] + R4*py[u] + R5*pz[u] - ty - qy[u];
            float dz = R6*px[u] + R7*py[u] + R8*pz[u] - tz - qz[u];
            float d2 = dx*dx + dy*dy + dz*dz;
            acc2 += w[4*k+u] / (1.0f + d2 * inv);
        }
    }
    __syncthreads();   // lds reuse barrier
    float a2[1] = {acc2};
    block_reduce<1>(a2, lds);
    if (tid == 0)
        out[b] = (cnt > 0.0f) ? a2[0] / fmaxf(cnt, 1.0f) : 0.0f;
}

// ---------------- launcher ----------------
extern "C" void kernel_launch(void* const* d_in, const int* in_sizes, int n_in,
                              void* d_out, int out_size, void* d_ws, size_t ws_size,
                              hipStream_t stream) {
    const float* P = (const float*)d_in[0];
    const float* Q = (const float*)d_in[1];
    const void* cm = d_in[2];
    const void* rm = d_in[3];
    float* out = (float*)d_out;

    k_fused<<<BATCH, TPB, 0, stream>>>(P, Q, cm, rm, out);
}

// Round 10
// 29.563 us; speedup vs baseline: 1.7536x; 1.0187x over previous
//
#include <hip/hip_runtime.h>
#include <hip/hip_fp16.h>
#include <math.h>

#define BATCH 512
#define SEQL  2048
#define NPTS  (SEQL*3)        // 6144 points per batch
#define NFLT  (NPTS*3)        // 18432 floats per batch per tensor
#define NGRP  (NPTS/4)        // 1536 groups of 4 points
#define TPB   512
#define NWAVE (TPB/64)

// ---------------- fp16 pack/unpack for the LDS stash ----------------
__device__ __forceinline__ uint2 pack4(float4 v) {
    __half2 lo = __floats2half2_rn(v.x, v.y);
    __half2 hi = __floats2half2_rn(v.z, v.w);
    uint2 r;
    r.x = *(unsigned int*)&lo;
    r.y = *(unsigned int*)&hi;
    return r;
}
__device__ __forceinline__ float4 unpack4(uint2 u) {
    __half2 lo = *(__half2*)&u.x;
    __half2 hi = *(__half2*)&u.y;
    float2 a = __half22float2(lo);
    float2 b = __half22float2(hi);
    return make_float4(a.x, a.y, b.x, b.y);
}

// ---------------- mask dtype detection ----------------
// flag: 0 = int32 {0,1}, 1 = uint8 {0,1}, 2 = float32
__device__ __forceinline__ int detect_flag(const void* cm, int* slds) {
    unsigned int v = ((const unsigned int*)cm)[threadIdx.x & 255];
    bool vi = (v <= 1u);
    bool vb = ((v & 0xFEFEFEFEu) == 0u);
    bool wi = __all(vi);
    bool wb = __all(vb);
    int wid = threadIdx.x >> 6;
    if ((threadIdx.x & 63) == 0) slds[wid] = (wi ? 1 : 0) | (wb ? 2 : 0);
    __syncthreads();
    if (threadIdx.x == 0) {
        int m = 3;
        for (int w = 0; w < (int)(blockDim.x >> 6); ++w) m &= slds[w];
        slds[8] = (m & 1) ? 0 : ((m & 2) ? 1 : 2);
    }
    __syncthreads();
    return slds[8];
}

// ---------------- reduction ----------------
template <int K>
__device__ __forceinline__ void block_reduce(float* acc, float* lds) {
#pragma unroll
    for (int k = 0; k < K; ++k) {
#pragma unroll
        for (int off = 32; off > 0; off >>= 1)
            acc[k] += __shfl_down(acc[k], off, 64);
    }
    int lane = threadIdx.x & 63;
    int wid  = threadIdx.x >> 6;
    if (lane == 0) {
#pragma unroll
        for (int k = 0; k < K; ++k) lds[wid * K + k] = acc[k];
    }
    __syncthreads();
    if (threadIdx.x == 0) {
#pragma unroll
        for (int k = 0; k < K; ++k) {
            float s = 0.f;
#pragma unroll
            for (int w = 0; w < NWAVE; ++w) s += lds[w * K + k];
            acc[k] = s;
        }
    }
}

__device__ __forceinline__ void accum_pt(float* a, float w,
                                         float px, float py, float pz,
                                         float qx, float qy, float qz) {
    a[0] += w;
    float wpx = w * px, wpy = w * py, wpz = w * pz;
    a[1] += wpx; a[2] += wpy; a[3] += wpz;
    a[4] += w * qx; a[5] += w * qy; a[6] += w * qz;
    a[7]  += wpx * qx; a[8]  += wpx * qy; a[9]  += wpx * qz;
    a[10] += wpy * qx; a[11] += wpy * qy; a[12] += wpy * qz;
    a[13] += wpz * qx; a[14] += wpz * qy; a[15] += wpz * qz;
}

// ---------------- closed-form 3x3 Kabsch, all scalars, no runtime indexing ----
// out prm: [0..8]=R, [9..11]=t (R*muP - muQ), [12]=1/d0^2, [13]=cnt
__device__ void kabsch_params(const float* s, float* o) {
    double cnt = (double)s[0];
    double cs = fmax(cnt, 1.0);
    double mup0 = (double)s[1] / cs, mup1 = (double)s[2] / cs, mup2 = (double)s[3] / cs;
    double muq0 = (double)s[4] / cs, muq1 = (double)s[5] / cs, muq2 = (double)s[6] / cs;

    double h00 = (double)s[7]  - cnt * mup0 * muq0;
    double h01 = (double)s[8]  - cnt * mup0 * muq1;
    double h02 = (double)s[9]  - cnt * mup0 * muq2;
    double h10 = (double)s[10] - cnt * mup1 * muq0;
    double h11 = (double)s[11] - cnt * mup1 * muq1;
    double h12 = (double)s[12] - cnt * mup1 * muq2;
    double h20 = (double)s[13] - cnt * mup2 * muq0;
    double h21 = (double)s[14] - cnt * mup2 * muq1;
    double h22 = (double)s[15] - cnt * mup2 * muq2;

    double a00 = h00*h00 + h10*h10 + h20*h20;
    double a01 = h00*h01 + h10*h11 + h20*h21;
    double a02 = h00*h02 + h10*h12 + h20*h22;
    double a11 = h01*h01 + h11*h11 + h21*h21;
    double a12 = h01*h02 + h11*h12 + h21*h22;
    double a22 = h02*h02 + h12*h12 + h22*h22;

    double q3  = (a00 + a11 + a22) / 3.0;
    double pp1 = a01*a01 + a02*a02 + a12*a12;
    double b00 = a00 - q3, b11 = a11 - q3, b22 = a22 - q3;
    double pp2 = b00*b00 + b11*b11 + b22*b22 + 2.0 * pp1;

    double l0, l1, l2;
    double v1x, v1y, v1z, v2x, v2y, v2z, v3x, v3y, v3z;
    if (pp2 <= 1e-24 * (q3 * q3) + 1e-290) {
        l0 = l1 = l2 = q3;
        v1x = 1; v1y = 0; v1z = 0;
        v2x = 0; v2y = 1; v2z = 0;
        v3x = 0; v3y = 0; v3z = 1;
    } else {
        double p = sqrt(pp2 / 6.0), invp = 1.0 / p;
        double c00 = b00*invp, c01 = a01*invp, c02 = a02*invp;
        double c11 = b11*invp, c12 = a12*invp, c22 = b22*invp;
        double detB = c00*(c11*c22 - c12*c12) - c01*(c01*c22 - c12*c02)
                    + c02*(c01*c12 - c11*c02);
        double r = fmin(1.0, fmax(-1.0, detB * 0.5));
        double phi = acos(r) / 3.0;
        l0 = q3 + 2.0 * p * cos(phi);
        l2 = q3 + 2.0 * p * cos(phi + 2.0943951023931953);  // +2pi/3
        l1 = 3.0 * q3 - l0 - l2;

        double aa00 = a00*a00 + a01*a01 + a02*a02;
        double aa01 = a00*a01 + a01*a11 + a02*a12;
        double aa02 = a00*a02 + a01*a12 + a02*a22;
        double aa11 = a01*a01 + a11*a11 + a12*a12;
        double aa12 = a01*a02 + a11*a12 + a12*a22;
        double aa22 = a02*a02 + a12*a12 + a22*a22;

        double s12 = l1 + l2, p12 = l1 * l2;
        double m00 = aa00 - s12*a00 + p12;
        double m01 = aa01 - s12*a01;
        double m02 = aa02 - s12*a02;
        double m11 = aa11 - s12*a11 + p12;
        double m12 = aa12 - s12*a12;
        double m22 = aa22 - s12*a22 + p12;
        double n0 = m00*m00 + m01*m01 + m02*m02;
        double n1 = m01*m01 + m11*m11 + m12*m12;
        double n2 = m02*m02 + m12*m12 + m22*m22;
        bool s0 = (n0 >= n1) && (n0 >= n2);
        bool sA = (n1 >= n2);
        v1x = s0 ? m00 : (sA ? m01 : m02);
        v1y = s0 ? m01 : (sA ? m11 : m12);
        v1z = s0 ? m02 : (sA ? m12 : m22);
        double n1v = sqrt(v1x*v1x + v1y*v1y + v1z*v1z);
        if (n1v > 1e-150) { v1x /= n1v; v1y /= n1v; v1z /= n1v; }
        else { v1x = 1; v1y = 0; v1z = 0; }

        double s01 = l0 + l1, p01 = l0 * l1;
        double t00 = aa00 - s01*a00 + p01;
        double t01 = aa01 - s01*a01;
        double t02 = aa02 - s01*a02;
        double t11 = aa11 - s01*a11 + p01;
        double t12 = aa12 - s01*a12;
        double t22 = aa22 - s01*a22 + p01;
        double u0n = t00*t00 + t01*t01 + t02*t02;
        double u1n = t01*t01 + t11*t11 + t12*t12;
        double u2n = t02*t02 + t12*t12 + t22*t22;
        bool d0c = (u0n >= u1n) && (u0n >= u2n);
        bool dA = (u1n >= u2n);
        v3x = d0c ? t00 : (dA ? t01 : t02);
        v3y = d0c ? t01 : (dA ? t11 : t12);
        v3z = d0c ? t02 : (dA ? t12 : t22);
        double dot13 = v3x*v1x + v3y*v1y + v3z*v1z;
        v3x -= dot13 * v1x; v3y -= dot13 * v1y; v3z -= dot13 * v1z;
        double n3v = sqrt(v3x*v3x + v3y*v3y + v3z*v3z);
        if (n3v > 1e-150) { v3x /= n3v; v3y /= n3v; v3z /= n3v; }
        else {
            double A0 = fabs(v1x), A1 = fabs(v1y), A2 = fabs(v1z);
            double axx = 0, axy = 0, axz = 0;
            if (A0 <= A1 && A0 <= A2) axx = 1; else if (A1 <= A2) axy = 1; else axz = 1;
            double dd = axx*v1x + axy*v1y + axz*v1z;
            v3x = axx - dd*v1x; v3y = axy - dd*v1y; v3z = axz - dd*v1z;
            double nn = sqrt(v3x*v3x + v3y*v3y + v3z*v3z);
            v3x /= nn; v3y /= nn; v3z /= nn;
        }
        v2x = v3y*v1z - v3z*v1y;
        v2y = v3z*v1x - v3x*v1z;
        v2z = v3x*v1y - v3y*v1x;
    }

    double sv0 = sqrt(fmax(l0, 0.0));
    double sv1 = sqrt(fmax(l1, 0.0));
    double sv2 = sqrt(fmax(l2, 0.0));
    double eps = sv0 * 1e-12 + 1e-300;

    double u0x, u0y, u0z, u1x, u1y, u1z, u2x, u2y, u2z;
    {
        double hx = h00*v1x + h01*v1y + h02*v1z;
        double hy = h10*v1x + h11*v1y + h12*v1z;
        double hz = h20*v1x + h21*v1y + h22*v1z;
        if (sv0 > eps) {
            double ix = hx / sv0, iy = hy / sv0, iz = hz / sv0;
            double nn = sqrt(ix*ix + iy*iy + iz*iz);
            if (nn > 1e-300) { ix /= nn; iy /= nn; iz /= nn; }
            u0x = ix; u0y = iy; u0z = iz;
        } else { u0x = 1; u0y = 0; u0z = 0; }
    }
    {
        double hx = h00*v2x + h01*v2y + h02*v2z;
        double hy = h10*v2x + h11*v2y + h12*v2z;
        double hz = h20*v2x + h21*v2y + h22*v2z;
        if (sv1 > eps) {
            double ix = hx / sv1, iy = hy / sv1, iz = hz / sv1;
            double nn = sqrt(ix*ix + iy*iy + iz*iz);
            if (nn > 1e-300) { ix /= nn; iy /= nn; iz /= nn; }
            u1x = ix; u1y = iy; u1z = iz;
        } else {
            double A0 = fabs(u0x), A1 = fabs(u0y), A2 = fabs(u0z);
            double axx = 0, axy = 0, axz = 0;
            if (A0 <= A1 && A0 <= A2) axx = 1; else if (A1 <= A2) axy = 1; else axz = 1;
            double cx = u0y*axz - u0z*axy;
            double cy = u0z*axx - u0x*axz;
            double cz = u0x*axy - u0y*axx;
            double nn = sqrt(cx*cx + cy*cy + cz*cz);
            if (nn > 1e-300) { cx /= nn; cy /= nn; cz /= nn; }
            u1x = cx; u1y = cy; u1z = cz;
        }
    }
    {
        double hx = h00*v3x + h01*v3y + h02*v3z;
        double hy = h10*v3x + h11*v3y + h12*v3z;
        double hz = h20*v3x + h21*v3y + h22*v3z;
        if (sv2 > eps) {
            double ix = hx / sv2, iy = hy / sv2, iz = hz / sv2;
            double nn = sqrt(ix*ix + iy*iy + iz*iz);
            if (nn > 1e-300) { ix /= nn; iy /= nn; iz /= nn; }
            u2x = ix; u2y = iy; u2z = iz;
        } else {
            u2x = u0y*u1z - u0z*u1y;
            u2y = u0z*u1x - u0x*u1z;
            u2z = u0x*u1y - u0y*u1x;
            double nn = sqrt(u2x*u2x + u2y*u2y + u2z*u2z);
            if (nn > 1e-300) { u2x /= nn; u2y /= nn; u2z /= nn; }
        }
    }

    double detH = h00*(h11*h22 - h12*h21) - h01*(h10*h22 - h12*h20)
                + h02*(h10*h21 - h11*h20);
    double e2 = (detH > 0.0) ? 1.0 : ((detH < 0.0) ? -1.0 : 0.0);

    double R00 = v1x*u0x + v2x*u1x + e2*v3x*u2x;
    double R01 = v1x*u0y + v2x*u1y + e2*v3x*u2y;
    double R02 = v1x*u0z + v2x*u1z + e2*v3x*u2z;
    double R10 = v1y*u0x + v2y*u1x + e2*v3y*u2x;
    double R11 = v1y*u0y + v2y*u1y + e2*v3y*u2y;
    double R12 = v1y*u0z + v2y*u1z + e2*v3y*u2z;
    double R20 = v1z*u0x + v2z*u1x + e2*v3z*u2x;
    double R21 = v1z*u0y + v2z*u1y + e2*v3z*u2y;
    double R22 = v1z*u0z + v2z*u1z + e2*v3z*u2z;

    o[0] = (float)R00; o[1] = (float)R01; o[2] = (float)R02;
    o[3] = (float)R10; o[4] = (float)R11; o[5] = (float)R12;
    o[6] = (float)R20; o[7] = (float)R21; o[8] = (float)R22;

    // t = R*muP - muQ  (phase C uses d = R*p - t - q)
    o[9]  = (float)(R00*mup0 + R01*mup1 + R02*mup2 - muq0);
    o[10] = (float)(R10*mup0 + R11*mup1 + R12*mup2 - muq1);
    o[11] = (float)(R20*mup0 + R21*mup1 + R22*mup2 - muq2);

    double n = (double)s[16];
    double d0 = 1.24 * cbrt(fmax(n - 15.0, 1e-3)) - 1.8;
    d0 = fmax(d0, 1e-3);
    o[12] = (float)(1.0 / (d0 * d0));
    o[13] = (float)cnt;
}

// ---------------- fused kernel ----------------
__global__ __launch_bounds__(TPB, 4) void k_fused(
    const float* __restrict__ P, const float* __restrict__ Q,
    const void* __restrict__ cmask, const void* __restrict__ rmask,
    float* __restrict__ out) {
    int b = blockIdx.x;
    int tid = threadIdx.x;
    __shared__ int slds[9];
    __shared__ float lds[NWAVE * 17];
    __shared__ float prm[14];
    // fp16 stash of ALL 1536 groups: 6 x 1536 x 8B = 73.7 KB
    __shared__ uint2 sP0[NGRP], sP1[NGRP], sP2[NGRP];
    __shared__ uint2 sQ0[NGRP], sQ1[NGRP], sQ2[NGRP];
    int flag = detect_flag(cmask, slds);

    const float4* Pv = (const float4*)(P + (size_t)b * NFLT);
    const float4* Qv = (const float4*)(Q + (size_t)b * NFLT);
    size_t gbase = (size_t)b * NGRP;

    // ---- phase A: hoist ALL loads, then stash + accumulate ----
    float4 p[9], q[9];
#pragma unroll
    for (int k = 0; k < 3; ++k) {
        int g = tid + k * TPB;
        p[3*k+0] = Pv[3*g+0]; p[3*k+1] = Pv[3*g+1]; p[3*k+2] = Pv[3*g+2];
        q[3*k+0] = Qv[3*g+0]; q[3*k+1] = Qv[3*g+1]; q[3*k+2] = Qv[3*g+2];
    }
    float w[12];
    float rescnt;
    {
        size_t rg = (size_t)b * (SEQL / 4) + tid;
        if (flag == 0) {
            const int4* cm4 = (const int4*)cmask;
            int4 m0 = cm4[gbase + tid], m1 = cm4[gbase + tid + TPB], m2 = cm4[gbase + tid + 2*TPB];
            int4 rv = ((const int4*)rmask)[rg];
            w[0]=m0.x?1.f:0.f; w[1]=m0.y?1.f:0.f; w[2]=m0.z?1.f:0.f; w[3]=m0.w?1.f:0.f;
            w[4]=m1.x?1.f:0.f; w[5]=m1.y?1.f:0.f; w[6]=m1.z?1.f:0.f; w[7]=m1.w?1.f:0.f;
            w[8]=m2.x?1.f:0.f; w[9]=m2.y?1.f:0.f; w[10]=m2.z?1.f:0.f; w[11]=m2.w?1.f:0.f;
            rescnt = (rv.x?1.f:0.f) + (rv.y?1.f:0.f) + (rv.z?1.f:0.f) + (rv.w?1.f:0.f);
        } else if (flag == 1) {
            const unsigned int* cmw = (const unsigned int*)cmask;
            unsigned int m0 = cmw[gbase + tid], m1 = cmw[gbase + tid + TPB], m2 = cmw[gbase + tid + 2*TPB];
            unsigned int rv = ((const unsigned int*)rmask)[rg];
            w[0]=(m0&0xFFu)?1.f:0.f; w[1]=(m0&0xFF00u)?1.f:0.f; w[2]=(m0&0xFF0000u)?1.f:0.f; w[3]=(m0&0xFF000000u)?1.f:0.f;
            w[4]=(m1&0xFFu)?1.f:0.f; w[5]=(m1&0xFF00u)?1.f:0.f; w[6]=(m1&0xFF0000u)?1.f:0.f; w[7]=(m1&0xFF000000u)?1.f:0.f;
            w[8]=(m2&0xFFu)?1.f:0.f; w[9]=(m2&0xFF00u)?1.f:0.f; w[10]=(m2&0xFF0000u)?1.f:0.f; w[11]=(m2&0xFF000000u)?1.f:0.f;
            rescnt = (float)__popc(rv);
        } else {
            const float4* cmf = (const float4*)cmask;
            float4 m0 = cmf[gbase + tid], m1 = cmf[gbase + tid + TPB], m2 = cmf[gbase + tid + 2*TPB];
            float4 rv = ((const float4*)rmask)[rg];
            w[0]=m0.x!=0.f?1.f:0.f; w[1]=m0.y!=0.f?1.f:0.f; w[2]=m0.z!=0.f?1.f:0.f; w[3]=m0.w!=0.f?1.f:0.f;
            w[4]=m1.x!=0.f?1.f:0.f; w[5]=m1.y!=0.f?1.f:0.f; w[6]=m1.z!=0.f?1.f:0.f; w[7]=m1.w!=0.f?1.f:0.f;
            w[8]=m2.x!=0.f?1.f:0.f; w[9]=m2.y!=0.f?1.f:0.f; w[10]=m2.z!=0.f?1.f:0.f; w[11]=m2.w!=0.f?1.f:0.f;
            rescnt = (rv.x!=0.f?1.f:0.f) + (rv.y!=0.f?1.f:0.f) + (rv.z!=0.f?1.f:0.f) + (rv.w!=0.f?1.f:0.f);
        }
    }

    // stash ALL groups as fp16
#pragma unroll
    for (int k = 0; k < 3; ++k) {
        int g = tid + k * TPB;
        sP0[g] = pack4(p[3*k+0]); sP1[g] = pack4(p[3*k+1]); sP2[g] = pack4(p[3*k+2]);
        sQ0[g] = pack4(q[3*k+0]); sQ1[g] = pack4(q[3*k+1]); sQ2[g] = pack4(q[3*k+2]);
    }

    float acc[17];
#pragma unroll
    for (int k = 0; k < 17; ++k) acc[k] = 0.0f;
    acc[16] = rescnt;

#pragma unroll
    for (int k = 0; k < 3; ++k) {
        float4 p0 = p[3*k+0], p1 = p[3*k+1], p2 = p[3*k+2];
        float4 q0 = q[3*k+0], q1 = q[3*k+1], q2 = q[3*k+2];
        accum_pt(acc, w[4*k+0], p0.x, p0.y, p0.z, q0.x, q0.y, q0.z);
        accum_pt(acc, w[4*k+1], p0.w, p1.x, p1.y, q0.w, q1.x, q1.y);
        accum_pt(acc, w[4*k+2], p1.z, p1.w, p2.x, q1.z, q1.w, q2.x);
        accum_pt(acc, w[4*k+3], p2.y, p2.z, p2.w, q2.y, q2.z, q2.w);
    }

    block_reduce<17>(acc, lds);

    // ---- phase B: thread 0, scratch-free closed-form Kabsch ----
    if (tid == 0) kabsch_params(acc, prm);
    __syncthreads();

    float R0 = prm[0], R1 = prm[1], R2 = prm[2];
    float R3 = prm[3], R4 = prm[4], R5 = prm[5];
    float R6 = prm[6], R7 = prm[7], R8 = prm[8];
    float tx = prm[9], ty = prm[10], tz = prm[11];
    float inv = prm[12], cnt = prm[13];

    // ---- phase C: rotate + TM, entirely from the fp16 LDS stash ----
    float acc2 = 0.0f;
#pragma unroll
    for (int k = 0; k < 3; ++k) {
        int g = tid + k * TPB;
        float4 p0 = unpack4(sP0[g]), p1 = unpack4(sP1[g]), p2 = unpack4(sP2[g]);
        float4 q0 = unpack4(sQ0[g]), q1 = unpack4(sQ1[g]), q2 = unpack4(sQ2[g]);
        float px[4] = {p0.x, p0.w, p1.z, p2.y};
        float py[4] = {p0.y, p1.x, p1.w, p2.z};
        float pz[4] = {p0.z, p1.y, p2.x, p2.w};
        float qx[4] = {q0.x, q0.w, q1.z, q2.y};
        float qy[4] = {q0.y, q1.x, q1.w, q2.z};
        float qz[4] = {q0.z, q1.y, q2.x, q2.w};
#pragma unroll
        for (int u = 0; u < 4; ++u) {
            float dx = R0*px[u] + R1*py[u] + R2*pz[u] - tx - qx[u];
            float dy = R3*px[u] + R4*py[u] + R5*pz[u] - ty - qy[u];
            float dz = R6*px[u] + R7*py[u] + R8*pz[u] - tz - qz[u];
            float d2 = dx*dx + dy*dy + dz*dz;
            acc2 += w[4*k+u] / (1.0f + d2 * inv);
        }
    }
    __syncthreads();   // lds reuse barrier
    float a2[1] = {acc2};
    block_reduce<1>(a2, lds);
    if (tid == 0)
        out[b] = (cnt > 0.0f) ? a2[0] / fmaxf(cnt, 1.0f) : 0.0f;
}

// ---------------- launcher ----------------
extern "C" void kernel_launch(void* const* d_in, const int* in_sizes, int n_in,
                              void* d_out, int out_size, void* d_ws, size_t ws_size,
                              hipStream_t stream) {
    const float* P = (const float*)d_in[0];
    const float* Q = (const float*)d_in[1];
    const void* cm = d_in[2];
    const void* rm = d_in[3];
    float* out = (float*)d_out;

    k_fused<<<BATCH, TPB, 0, stream>>>(P, Q, cm, rm, out);
}

// Round 11
// 29.158 us; speedup vs baseline: 1.7779x; 1.0139x over previous
//
#include <hip/hip_runtime.h>
#include <hip/hip_fp16.h>
#include <math.h>

#define BATCH 512
#define SEQL  2048
#define NPTS  (SEQL*3)        // 6144 points per batch
#define NFLT  (NPTS*3)        // 18432 floats per batch per tensor
#define NGRP  (NPTS/4)        // 1536 groups of 4 points
#define TPB   512
#define NWAVE (TPB/64)

// ---------------- fp16 pack/unpack for the LDS stash ----------------
__device__ __forceinline__ uint2 pack4(float4 v) {
    __half2 lo = __floats2half2_rn(v.x, v.y);
    __half2 hi = __floats2half2_rn(v.z, v.w);
    uint2 r;
    r.x = *(unsigned int*)&lo;
    r.y = *(unsigned int*)&hi;
    return r;
}
__device__ __forceinline__ float4 unpack4(uint2 u) {
    __half2 lo = *(__half2*)&u.x;
    __half2 hi = *(__half2*)&u.y;
    float2 a = __half22float2(lo);
    float2 b = __half22float2(hi);
    return make_float4(a.x, a.y, b.x, b.y);
}

// ---------------- mask dtype detection (per-wave, barrier-free) ----------------
// flag: 0 = int32 {0,1}, 1 = uint8 {0,1}, 2 = float32
// Each lane checks one of the first 64 words; __all makes it wave-uniform.
// int32 0/1 word is <=1; packed-byte words (e.g. 0x01010101) fail; fp32 fails both.
__device__ __forceinline__ int detect_flag_wave(const void* cm) {
    unsigned int v = ((const unsigned int*)cm)[threadIdx.x & 63];
    bool wi = __all(v <= 1u);
    bool wb = __all((v & 0xFEFEFEFEu) == 0u);
    return wi ? 0 : (wb ? 1 : 2);
}

// ---------------- reduction ----------------
template <int K>
__device__ __forceinline__ void block_reduce(float* acc, float* lds) {
#pragma unroll
    for (int k = 0; k < K; ++k) {
#pragma unroll
        for (int off = 32; off > 0; off >>= 1)
            acc[k] += __shfl_down(acc[k], off, 64);
    }
    int lane = threadIdx.x & 63;
    int wid  = threadIdx.x >> 6;
    if (lane == 0) {
#pragma unroll
        for (int k = 0; k < K; ++k) lds[wid * K + k] = acc[k];
    }
    __syncthreads();
    if (threadIdx.x == 0) {
#pragma unroll
        for (int k = 0; k < K; ++k) {
            float s = 0.f;
#pragma unroll
            for (int w = 0; w < NWAVE; ++w) s += lds[w * K + k];
            acc[k] = s;
        }
    }
}

__device__ __forceinline__ void accum_pt(float* a, float w,
                                         float px, float py, float pz,
                                         float qx, float qy, float qz) {
    a[0] += w;
    float wpx = w * px, wpy = w * py, wpz = w * pz;
    a[1] += wpx; a[2] += wpy; a[3] += wpz;
    a[4] += w * qx; a[5] += w * qy; a[6] += w * qz;
    a[7]  += wpx * qx; a[8]  += wpx * qy; a[9]  += wpx * qz;
    a[10] += wpy * qx; a[11] += wpy * qy; a[12] += wpy * qz;
    a[13] += wpz * qx; a[14] += wpz * qy; a[15] += wpz * qz;
}

// ---------------- closed-form 3x3 Kabsch, all scalars, no runtime indexing ----
// out prm: [0..8]=R, [9..11]=t (R*muP - muQ), [12]=1/d0^2, [13]=cnt
__device__ void kabsch_params(const float* s, float* o) {
    double cnt = (double)s[0];
    double cs = fmax(cnt, 1.0);
    double mup0 = (double)s[1] / cs, mup1 = (double)s[2] / cs, mup2 = (double)s[3] / cs;
    double muq0 = (double)s[4] / cs, muq1 = (double)s[5] / cs, muq2 = (double)s[6] / cs;

    double h00 = (double)s[7]  - cnt * mup0 * muq0;
    double h01 = (double)s[8]  - cnt * mup0 * muq1;
    double h02 = (double)s[9]  - cnt * mup0 * muq2;
    double h10 = (double)s[10] - cnt * mup1 * muq0;
    double h11 = (double)s[11] - cnt * mup1 * muq1;
    double h12 = (double)s[12] - cnt * mup1 * muq2;
    double h20 = (double)s[13] - cnt * mup2 * muq0;
    double h21 = (double)s[14] - cnt * mup2 * muq1;
    double h22 = (double)s[15] - cnt * mup2 * muq2;

    double a00 = h00*h00 + h10*h10 + h20*h20;
    double a01 = h00*h01 + h10*h11 + h20*h21;
    double a02 = h00*h02 + h10*h12 + h20*h22;
    double a11 = h01*h01 + h11*h11 + h21*h21;
    double a12 = h01*h02 + h11*h12 + h21*h22;
    double a22 = h02*h02 + h12*h12 + h22*h22;

    double q3  = (a00 + a11 + a22) / 3.0;
    double pp1 = a01*a01 + a02*a02 + a12*a12;
    double b00 = a00 - q3, b11 = a11 - q3, b22 = a22 - q3;
    double pp2 = b00*b00 + b11*b11 + b22*b22 + 2.0 * pp1;

    double l0, l1, l2;
    double v1x, v1y, v1z, v2x, v2y, v2z, v3x, v3y, v3z;
    if (pp2 <= 1e-24 * (q3 * q3) + 1e-290) {
        l0 = l1 = l2 = q3;
        v1x = 1; v1y = 0; v1z = 0;
        v2x = 0; v2y = 1; v2z = 0;
        v3x = 0; v3y = 0; v3z = 1;
    } else {
        double p = sqrt(pp2 / 6.0), invp = 1.0 / p;
        double c00 = b00*invp, c01 = a01*invp, c02 = a02*invp;
        double c11 = b11*invp, c12 = a12*invp, c22 = b22*invp;
        double detB = c00*(c11*c22 - c12*c12) - c01*(c01*c22 - c12*c02)
                    + c02*(c01*c12 - c11*c02);
        double r = fmin(1.0, fmax(-1.0, detB * 0.5));
        double phi = acos(r) / 3.0;
        l0 = q3 + 2.0 * p * cos(phi);
        l2 = q3 + 2.0 * p * cos(phi + 2.0943951023931953);  // +2pi/3
        l1 = 3.0 * q3 - l0 - l2;

        double aa00 = a00*a00 + a01*a01 + a02*a02;
        double aa01 = a00*a01 + a01*a11 + a02*a12;
        double aa02 = a00*a02 + a01*a12 + a02*a22;
        double aa11 = a01*a01 + a11*a11 + a12*a12;
        double aa12 = a01*a02 + a11*a12 + a12*a22;
        double aa22 = a02*a02 + a12*a12 + a22*a22;

        double s12 = l1 + l2, p12 = l1 * l2;
        double m00 = aa00 - s12*a00 + p12;
        double m01 = aa01 - s12*a01;
        double m02 = aa02 - s12*a02;
        double m11 = aa11 - s12*a11 + p12;
        double m12 = aa12 - s12*a12;
        double m22 = aa22 - s12*a22 + p12;
        double n0 = m00*m00 + m01*m01 + m02*m02;
        double n1 = m01*m01 + m11*m11 + m12*m12;
        double n2 = m02*m02 + m12*m12 + m22*m22;
        bool s0 = (n0 >= n1) && (n0 >= n2);
        bool sA = (n1 >= n2);
        v1x = s0 ? m00 : (sA ? m01 : m02);
        v1y = s0 ? m01 : (sA ? m11 : m12);
        v1z = s0 ? m02 : (sA ? m12 : m22);
        double n1v = sqrt(v1x*v1x + v1y*v1y + v1z*v1z);
        if (n1v > 1e-150) { v1x /= n1v; v1y /= n1v; v1z /= n1v; }
        else { v1x = 1; v1y = 0; v1z = 0; }

        double s01 = l0 + l1, p01 = l0 * l1;
        double t00 = aa00 - s01*a00 + p01;
        double t01 = aa01 - s01*a01;
        double t02 = aa02 - s01*a02;
        double t11 = aa11 - s01*a11 + p01;
        double t12 = aa12 - s01*a12;
        double t22 = aa22 - s01*a22 + p01;
        double u0n = t00*t00 + t01*t01 + t02*t02;
        double u1n = t01*t01 + t11*t11 + t12*t12;
        double u2n = t02*t02 + t12*t12 + t22*t22;
        bool d0c = (u0n >= u1n) && (u0n >= u2n);
        bool dA = (u1n >= u2n);
        v3x = d0c ? t00 : (dA ? t01 : t02);
        v3y = d0c ? t01 : (dA ? t11 : t12);
        v3z = d0c ? t02 : (dA ? t12 : t22);
        double dot13 = v3x*v1x + v3y*v1y + v3z*v1z;
        v3x -= dot13 * v1x; v3y -= dot13 * v1y; v3z -= dot13 * v1z;
        double n3v = sqrt(v3x*v3x + v3y*v3y + v3z*v3z);
        if (n3v > 1e-150) { v3x /= n3v; v3y /= n3v; v3z /= n3v; }
        else {
            double A0 = fabs(v1x), A1 = fabs(v1y), A2 = fabs(v1z);
            double axx = 0, axy = 0, axz = 0;
            if (A0 <= A1 && A0 <= A2) axx = 1; else if (A1 <= A2) axy = 1; else axz = 1;
            double dd = axx*v1x + axy*v1y + axz*v1z;
            v3x = axx - dd*v1x; v3y = axy - dd*v1y; v3z = axz - dd*v1z;
            double nn = sqrt(v3x*v3x + v3y*v3y + v3z*v3z);
            v3x /= nn; v3y /= nn; v3z /= nn;
        }
        v2x = v3y*v1z - v3z*v1y;
        v2y = v3z*v1x - v3x*v1z;
        v2z = v3x*v1y - v3y*v1x;
    }

    double sv0 = sqrt(fmax(l0, 0.0));
    double sv1 = sqrt(fmax(l1, 0.0));
    double sv2 = sqrt(fmax(l2, 0.0));
    double eps = sv0 * 1e-12 + 1e-300;

    double u0x, u0y, u0z, u1x, u1y, u1z, u2x, u2y, u2z;
    {
        double hx = h00*v1x + h01*v1y + h02*v1z;
        double hy = h10*v1x + h11*v1y + h12*v1z;
        double hz = h20*v1x + h21*v1y + h22*v1z;
        if (sv0 > eps) {
            double ix = hx / sv0, iy = hy / sv0, iz = hz / sv0;
            double nn = sqrt(ix*ix + iy*iy + iz*iz);
            if (nn > 1e-300) { ix /= nn; iy /= nn; iz /= nn; }
            u0x = ix; u0y = iy; u0z = iz;
        } else { u0x = 1; u0y = 0; u0z = 0; }
    }
    {
        double hx = h00*v2x + h01*v2y + h02*v2z;
        double hy = h10*v2x + h11*v2y + h12*v2z;
        double hz = h20*v2x + h21*v2y + h22*v2z;
        if (sv1 > eps) {
            double ix = hx / sv1, iy = hy / sv1, iz = hz / sv1;
            double nn = sqrt(ix*ix + iy*iy + iz*iz);
            if (nn > 1e-300) { ix /= nn; iy /= nn; iz /= nn; }
            u1x = ix; u1y = iy; u1z = iz;
        } else {
            double A0 = fabs(u0x), A1 = fabs(u0y), A2 = fabs(u0z);
            double axx = 0, axy = 0, axz = 0;
            if (A0 <= A1 && A0 <= A2) axx = 1; else if (A1 <= A2) axy = 1; else axz = 1;
            double cx = u0y*axz - u0z*axy;
            double cy = u0z*axx - u0x*axz;
            double cz = u0x*axy - u0y*axx;
            double nn = sqrt(cx*cx + cy*cy + cz*cz);
            if (nn > 1e-300) { cx /= nn; cy /= nn; cz /= nn; }
            u1x = cx; u1y = cy; u1z = cz;
        }
    }
    {
        double hx = h00*v3x + h01*v3y + h02*v3z;
        double hy = h10*v3x + h11*v3y + h12*v3z;
        double hz = h20*v3x + h21*v3y + h22*v3z;
        if (sv2 > eps) {
            double ix = hx / sv2, iy = hy / sv2, iz = hz / sv2;
            double nn = sqrt(ix*ix + iy*iy + iz*iz);
            if (nn > 1e-300) { ix /= nn; iy /= nn; iz /= nn; }
            u2x = ix; u2y = iy; u2z = iz;
        } else {
            u2x = u0y*u1z - u0z*u1y;
            u2y = u0z*u1x - u0x*u1z;
            u2z = u0x*u1y - u0y*u1x;
            double nn = sqrt(u2x*u2x + u2y*u2y + u2z*u2z);
            if (nn > 1e-300) { u2x /= nn; u2y /= nn; u2z /= nn; }
        }
    }

    double detH = h00*(h11*h22 - h12*h21) - h01*(h10*h22 - h12*h20)
                + h02*(h10*h21 - h11*h20);
    double e2 = (detH > 0.0) ? 1.0 : ((detH < 0.0) ? -1.0 : 0.0);

    double R00 = v1x*u0x + v2x*u1x + e2*v3x*u2x;
    double R01 = v1x*u0y + v2x*u1y + e2*v3x*u2y;
    double R02 = v1x*u0z + v2x*u1z + e2*v3x*u2z;
    double R10 = v1y*u0x + v2y*u1x + e2*v3y*u2x;
    double R11 = v1y*u0y + v2y*u1y + e2*v3y*u2y;
    double R12 = v1y*u0z + v2y*u1z + e2*v3y*u2z;
    double R20 = v1z*u0x + v2z*u1x + e2*v3z*u2x;
    double R21 = v1z*u0y + v2z*u1y + e2*v3z*u2y;
    double R22 = v1z*u0z + v2z*u1z + e2*v3z*u2z;

    o[0] = (float)R00; o[1] = (float)R01; o[2] = (float)R02;
    o[3] = (float)R10; o[4] = (float)R11; o[5] = (float)R12;
    o[6] = (float)R20; o[7] = (float)R21; o[8] = (float)R22;

    // t = R*muP - muQ  (phase C uses d = R*p - t - q)
    o[9]  = (float)(R00*mup0 + R01*mup1 + R02*mup2 - muq0);
    o[10] = (float)(R10*mup0 + R11*mup1 + R12*mup2 - muq1);
    o[11] = (float)(R20*mup0 + R21*mup1 + R22*mup2 - muq2);

    double n = (double)s[16];
    double d0 = 1.24 * cbrt(fmax(n - 15.0, 1e-3)) - 1.8;
    d0 = fmax(d0, 1e-3);
    o[12] = (float)(1.0 / (d0 * d0));
    o[13] = (float)cnt;
}

// ---------------- fused kernel ----------------
// __launch_bounds__(512, 2): grid=512 means only 2 blocks/CU are reachable,
// so demand exactly that occupancy -> 128-VGPR cap, letting the 22-load
// hoist stay register-resident (at (512,4)'s 64-VGPR cap the compiler
// re-serialized the loads: R10 showed VGPR_Count=64 and ~40% HBM duty).
__global__ __launch_bounds__(TPB, 2) void k_fused(
    const float* __restrict__ P, const float* __restrict__ Q,
    const void* __restrict__ cmask, const void* __restrict__ rmask,
    float* __restrict__ out) {
    int b = blockIdx.x;
    int tid = threadIdx.x;
    __shared__ float lds[NWAVE * 17];
    __shared__ float prm[14];
    // fp16 stash of ALL 1536 groups: 6 x 1536 x 8B = 73.7 KB
    __shared__ uint2 sP0[NGRP], sP1[NGRP], sP2[NGRP];
    __shared__ uint2 sQ0[NGRP], sQ1[NGRP], sQ2[NGRP];
    int flag = detect_flag_wave(cmask);   // per-wave, no barrier

    const float4* Pv = (const float4*)(P + (size_t)b * NFLT);
    const float4* Qv = (const float4*)(Q + (size_t)b * NFLT);
    size_t gbase = (size_t)b * NGRP;

    // ---- phase A: hoist ALL loads, then stash + accumulate ----
    float4 p[9], q[9];
#pragma unroll
    for (int k = 0; k < 3; ++k) {
        int g = tid + k * TPB;
        p[3*k+0] = Pv[3*g+0]; p[3*k+1] = Pv[3*g+1]; p[3*k+2] = Pv[3*g+2];
        q[3*k+0] = Qv[3*g+0]; q[3*k+1] = Qv[3*g+1]; q[3*k+2] = Qv[3*g+2];
    }
    float w[12];
    float rescnt;
    {
        size_t rg = (size_t)b * (SEQL / 4) + tid;
        if (flag == 0) {
            const int4* cm4 = (const int4*)cmask;
            int4 m0 = cm4[gbase + tid], m1 = cm4[gbase + tid + TPB], m2 = cm4[gbase + tid + 2*TPB];
            int4 rv = ((const int4*)rmask)[rg];
            w[0]=m0.x?1.f:0.f; w[1]=m0.y?1.f:0.f; w[2]=m0.z?1.f:0.f; w[3]=m0.w?1.f:0.f;
            w[4]=m1.x?1.f:0.f; w[5]=m1.y?1.f:0.f; w[6]=m1.z?1.f:0.f; w[7]=m1.w?1.f:0.f;
            w[8]=m2.x?1.f:0.f; w[9]=m2.y?1.f:0.f; w[10]=m2.z?1.f:0.f; w[11]=m2.w?1.f:0.f;
            rescnt = (rv.x?1.f:0.f) + (rv.y?1.f:0.f) + (rv.z?1.f:0.f) + (rv.w?1.f:0.f);
        } else if (flag == 1) {
            const unsigned int* cmw = (const unsigned int*)cmask;
            unsigned int m0 = cmw[gbase + tid], m1 = cmw[gbase + tid + TPB], m2 = cmw[gbase + tid + 2*TPB];
            unsigned int rv = ((const unsigned int*)rmask)[rg];
            w[0]=(m0&0xFFu)?1.f:0.f; w[1]=(m0&0xFF00u)?1.f:0.f; w[2]=(m0&0xFF0000u)?1.f:0.f; w[3]=(m0&0xFF000000u)?1.f:0.f;
            w[4]=(m1&0xFFu)?1.f:0.f; w[5]=(m1&0xFF00u)?1.f:0.f; w[6]=(m1&0xFF0000u)?1.f:0.f; w[7]=(m1&0xFF000000u)?1.f:0.f;
            w[8]=(m2&0xFFu)?1.f:0.f; w[9]=(m2&0xFF00u)?1.f:0.f; w[10]=(m2&0xFF0000u)?1.f:0.f; w[11]=(m2&0xFF000000u)?1.f:0.f;
            rescnt = (float)__popc(rv);
        } else {
            const float4* cmf = (const float4*)cmask;
            float4 m0 = cmf[gbase + tid], m1 = cmf[gbase + tid + TPB], m2 = cmf[gbase + tid + 2*TPB];
            float4 rv = ((const float4*)rmask)[rg];
            w[0]=m0.x!=0.f?1.f:0.f; w[1]=m0.y!=0.f?1.f:0.f; w[2]=m0.z!=0.f?1.f:0.f; w[3]=m0.w!=0.f?1.f:0.f;
            w[4]=m1.x!=0.f?1.f:0.f; w[5]=m1.y!=0.f?1.f:0.f; w[6]=m1.z!=0.f?1.f:0.f; w[7]=m1.w!=0.f?1.f:0.f;
            w[8]=m2.x!=0.f?1.f:0.f; w[9]=m2.y!=0.f?1.f:0.f; w[10]=m2.z!=0.f?1.f:0.f; w[11]=m2.w!=0.f?1.f:0.f;
            rescnt = (rv.x!=0.f?1.f:0.f) + (rv.y!=0.f?1.f:0.f) + (rv.z!=0.f?1.f:0.f) + (rv.w!=0.f?1.f:0.f);
        }
    }

    // stash ALL groups as fp16
#pragma unroll
    for (int k = 0; k < 3; ++k) {
        int g = tid + k * TPB;
        sP0[g] = pack4(p[3*k+0]); sP1[g] = pack4(p[3*k+1]); sP2[g] = pack4(p[3*k+2]);
        sQ0[g] = pack4(q[3*k+0]); sQ1[g] = pack4(q[3*k+1]); sQ2[g] = pack4(q[3*k+2]);
    }

    float acc[17];
#pragma unroll
    for (int k = 0; k < 17; ++k) acc[k] = 0.0f;
    acc[16] = rescnt;

#pragma unroll
    for (int k = 0; k < 3; ++k) {
        float4 p0 = p[3*k+0], p1 = p[3*k+1], p2 = p[3*k+2];
        float4 q0 = q[3*k+0], q1 = q[3*k+1], q2 = q[3*k+2];
        accum_pt(acc, w[4*k+0], p0.x, p0.y, p0.z, q0.x, q0.y, q0.z);
        accum_pt(acc, w[4*k+1], p0.w, p1.x, p1.y, q0.w, q1.x, q1.y);
        accum_pt(acc, w[4*k+2], p1.z, p1.w, p2.x, q1.z, q1.w, q2.x);
        accum_pt(acc, w[4*k+3], p2.y, p2.z, p2.w, q2.y, q2.z, q2.w);
    }

    block_reduce<17>(acc, lds);

    // ---- phase B: thread 0, scratch-free closed-form Kabsch ----
    if (tid == 0) kabsch_params(acc, prm);
    __syncthreads();

    float R0 = prm[0], R1 = prm[1], R2 = prm[2];
    float R3 = prm[3], R4 = prm[4], R5 = prm[5];
    float R6 = prm[6], R7 = prm[7], R8 = prm[8];
    float tx = prm[9], ty = prm[10], tz = prm[11];
    float inv = prm[12], cnt = prm[13];

    // ---- phase C: rotate + TM, entirely from the fp16 LDS stash ----
    float acc2 = 0.0f;
#pragma unroll
    for (int k = 0; k < 3; ++k) {
        int g = tid + k * TPB;
        float4 p0 = unpack4(sP0[g]), p1 = unpack4(sP1[g]), p2 = unpack4(sP2[g]);
        float4 q0 = unpack4(sQ0[g]), q1 = unpack4(sQ1[g]), q2 = unpack4(sQ2[g]);
        float px[4] = {p0.x, p0.w, p1.z, p2.y};
        float py[4] = {p0.y, p1.x, p1.w, p2.z};
        float pz[4] = {p0.z, p1.y, p2.x, p2.w};
        float qx[4] = {q0.x, q0.w, q1.z, q2.y};
        float qy[4] = {q0.y, q1.x, q1.w, q2.z};
        float qz[4] = {q0.z, q1.y, q2.x, q2.w};
#pragma unroll
        for (int u = 0; u < 4; ++u) {
            float dx = R0*px[u] + R1*py[u] + R2*pz[u] - tx - qx[u];
            float dy = R3*px[u] + R4*py[u] + R5*pz[u] - ty - qy[u];
            float dz = R6*px[u] + R7*py[u] + R8*pz[u] - tz - qz[u];
            float d2 = dx*dx + dy*dy + dz*dz;
            acc2 += w[4*k+u] / (1.0f + d2 * inv);
        }
    }
    __syncthreads();   // lds reuse barrier
    float a2[1] = {acc2};
    block_reduce<1>(a2, lds);
    if (tid == 0)
        out[b] = (cnt > 0.0f) ? a2[0] / fmaxf(cnt, 1.0f) : 0.0f;
}

// ---------------- launcher ----------------
extern "C" void kernel_launch(void* const* d_in, const int* in_sizes, int n_in,
                              void* d_out, int out_size, void* d_ws, size_t ws_size,
                              hipStream_t stream) {
    const float* P = (const float*)d_in[0];
    const float* Q = (const float*)d_in[1];
    const void* cm = d_in[2];
    const void* rm = d_in[3];
    float* out = (float*)d_out;

    k_fused<<<BATCH, TPB, 0, stream>>>(P, Q, cm, rm, out);
}